// Round 1
// baseline (672.515 us; speedup 1.0000x reference)
//
#include <hip/hip_runtime.h>
#include <math.h>

#define BN_EPS 1e-5f

// ---------------- CSR build ----------------
__global__ void count_dst_k(const int* __restrict__ dst, int* __restrict__ cnt, int E) {
  int i = blockIdx.x * blockDim.x + threadIdx.x;
  if (i < E) atomicAdd(&cnt[dst[i]], 1);
}

__global__ __launch_bounds__(1024) void scan_k(const int* __restrict__ cnt,
                                               int* __restrict__ rowptr,
                                               float* __restrict__ dinv, int n) {
  __shared__ int part[1024];
  int tid = threadIdx.x;
  int chunk = (n + 1023) / 1024;
  int beg = tid * chunk; if (beg > n) beg = n;
  int end = beg + chunk; if (end > n) end = n;
  int s = 0;
  for (int i = beg; i < end; ++i) s += cnt[i];
  part[tid] = s;
  __syncthreads();
  for (int o = 1; o < 1024; o <<= 1) {
    int v = (tid >= o) ? part[tid - o] : 0;
    __syncthreads();
    part[tid] += v;
    __syncthreads();
  }
  int run = (tid == 0) ? 0 : part[tid - 1];
  for (int i = beg; i < end; ++i) {
    int c = cnt[i];
    rowptr[i] = run;
    run += c;
    dinv[i] = rsqrtf((float)(c + 1));   // deg = in-degree + self-loop
  }
  if (tid == 1023) rowptr[n] = part[1023];
}

__global__ void fill_csr_k(const int* __restrict__ src, const int* __restrict__ dst,
                           const int* __restrict__ rowptr, int* __restrict__ fill,
                           int* __restrict__ csr_src, int E) {
  int i = blockIdx.x * blockDim.x + threadIdx.x;
  if (i < E) {
    int d = dst[i];
    int p = rowptr[d] + atomicAdd(&fill[d], 1);
    csr_src[p] = src[i];
  }
}

// ---------------- GEMM: Y[M,128] = X[M,128] @ W[128,128] (+bias) ----------------
// 64 rows/block, 256 threads. LDS: Xs 32KB + Ws(half-K) 32KB = 64KB -> 2 blocks/CU.
__global__ __launch_bounds__(256) void gemm128_k(const float* __restrict__ X,
                                                 const float* __restrict__ W,
                                                 const float* __restrict__ bias,
                                                 float* __restrict__ Y, int M) {
  __shared__ float Xs[64][128];
  __shared__ float Ws[64][128];
  int tid = threadIdx.x;
  int row0 = blockIdx.x * 64;
  // stage X tile (2048 float4, 8 per thread)
  for (int i = tid; i < 64 * 32; i += 256) {
    int r = i >> 5, c4 = i & 31;
    int gr = row0 + r;
    float4 v = make_float4(0.f, 0.f, 0.f, 0.f);
    if (gr < M) v = ((const float4*)X)[(size_t)gr * 32 + c4];
    ((float4*)&Xs[0][0])[i] = v;
  }
  int tx = tid & 31, ty = tid >> 5;
  float4 acc[8];
  #pragma unroll
  for (int r = 0; r < 8; ++r) acc[r] = make_float4(0.f, 0.f, 0.f, 0.f);
  for (int kh = 0; kh < 2; ++kh) {
    __syncthreads();   // kh=0: Xs visible; kh=1: prior Ws reads done
    for (int i = tid; i < 64 * 32; i += 256)
      ((float4*)&Ws[0][0])[i] = ((const float4*)W)[kh * 2048 + i];
    __syncthreads();
    #pragma unroll 4
    for (int k = 0; k < 64; ++k) {
      float4 b = *(const float4*)&Ws[k][tx * 4];
      #pragma unroll
      for (int r = 0; r < 8; ++r) {
        float a = Xs[ty * 8 + r][kh * 64 + k];
        acc[r].x = fmaf(a, b.x, acc[r].x);
        acc[r].y = fmaf(a, b.y, acc[r].y);
        acc[r].z = fmaf(a, b.z, acc[r].z);
        acc[r].w = fmaf(a, b.w, acc[r].w);
      }
    }
  }
  float4 bv = make_float4(0.f, 0.f, 0.f, 0.f);
  if (bias) bv = *(const float4*)&bias[tx * 4];
  #pragma unroll
  for (int r = 0; r < 8; ++r) {
    int gr = row0 + ty * 8 + r;
    if (gr < M) {
      float4 o = acc[r];
      o.x += bv.x; o.y += bv.y; o.z += bv.z; o.w += bv.w;
      ((float4*)Y)[(size_t)gr * 32 + tx] = o;
    }
  }
}

// ------------- per-node gather aggregate + bias + BN(eval) + ReLU -------------
// one wave per node; lane handles 2 channels (float2)
__global__ __launch_bounds__(256) void agg_bn_relu_k(const float* __restrict__ XW,
    const int* __restrict__ rowptr, const int* __restrict__ csr_src,
    const float* __restrict__ dinv,
    const float* __restrict__ bb, const float* __restrict__ g,
    const float* __restrict__ be, const float* __restrict__ mm,
    const float* __restrict__ vv,
    float* __restrict__ H, int n) {
  int wid = (blockIdx.x * 256 + threadIdx.x) >> 6;
  if (wid >= n) return;
  int lane = threadIdx.x & 63;
  const float2* XW2 = (const float2*)XW;
  float2 acc = make_float2(0.f, 0.f);
  int beg = rowptr[wid], end = rowptr[wid + 1];
  for (int i = beg; i < end; ++i) {
    int s = csr_src[i];
    float w = dinv[s];
    float2 xv = XW2[(size_t)s * 64 + lane];
    acc.x = fmaf(w, xv.x, acc.x);
    acc.y = fmaf(w, xv.y, acc.y);
  }
  float dn = dinv[wid];
  float2 xv = XW2[(size_t)wid * 64 + lane];
  acc.x = fmaf(dn, xv.x, acc.x);
  acc.y = fmaf(dn, xv.y, acc.y);
  acc.x *= dn; acc.y *= dn;
  int c = lane * 2;
  float s0 = g[c]     * rsqrtf(vv[c]     + BN_EPS);
  float s1 = g[c + 1] * rsqrtf(vv[c + 1] + BN_EPS);
  float o0 = (acc.x + bb[c]     - mm[c])     * s0 + be[c];
  float o1 = (acc.y + bb[c + 1] - mm[c + 1]) * s1 + be[c + 1];
  o0 = fmaxf(o0, 0.f);
  o1 = fmaxf(o1, 0.f);
  ((float2*)H)[(size_t)wid * 64 + lane] = make_float2(o0, o1);
}

// ------------- edge MLP: sigmoid(relu(A[s]+B[d]) . w2 + b2) -------------
// one wave per edge; lane handles 2 hidden channels
__global__ __launch_bounds__(256) void edge_mlp_k(const float* __restrict__ A,
    const float* __restrict__ B, const int* __restrict__ src,
    const int* __restrict__ dst, const float* __restrict__ w2,
    const float* __restrict__ b2, float* __restrict__ out, int E) {
  int e = (blockIdx.x * 256 + threadIdx.x) >> 6;
  if (e >= E) return;
  int lane = threadIdx.x & 63;
  int s = src[e], d = dst[e];
  float2 a = ((const float2*)A)[(size_t)s * 64 + lane];
  float2 b = ((const float2*)B)[(size_t)d * 64 + lane];
  float2 w = ((const float2*)w2)[lane];
  float h0 = fmaxf(a.x + b.x, 0.f);
  float h1 = fmaxf(a.y + b.y, 0.f);
  float p = fmaf(h0, w.x, h1 * w.y);
  #pragma unroll
  for (int o = 32; o > 0; o >>= 1) p += __shfl_xor(p, o);
  if (lane == 0) {
    float z = p + b2[0];
    out[e] = 1.f / (1.f + expf(-z));
  }
}

extern "C" void kernel_launch(void* const* d_in, const int* in_sizes, int n_in,
                              void* d_out, int out_size, void* d_ws, size_t ws_size,
                              hipStream_t stream) {
  const float* x    = (const float*)d_in[0];
  const int*   ei   = (const int*)d_in[1];
  const float* W1   = (const float*)d_in[2];
  const float* b1   = (const float*)d_in[3];
  const float* g1   = (const float*)d_in[4];
  const float* be1  = (const float*)d_in[5];
  const float* m1   = (const float*)d_in[6];
  const float* v1   = (const float*)d_in[7];
  const float* W2   = (const float*)d_in[8];
  const float* b2   = (const float*)d_in[9];
  const float* g2   = (const float*)d_in[10];
  const float* be2  = (const float*)d_in[11];
  const float* m2   = (const float*)d_in[12];
  const float* v2   = (const float*)d_in[13];
  const float* epW1 = (const float*)d_in[14];
  const float* epb1 = (const float*)d_in[15];
  const float* epW2 = (const float*)d_in[16];
  const float* epb2 = (const float*)d_in[17];

  int N = in_sizes[0] / 128;
  int E = in_sizes[1] / 2;
  const int* src = ei;
  const int* dst = ei + E;

  char* w = (char*)d_ws;
  size_t off = 0;
  auto carve = [&](size_t bytes) {
    void* p = w + off;
    off = (off + bytes + 255) & ~(size_t)255;
    return p;
  };
  float* bufX  = (float*)carve((size_t)N * 128 * 4);  // xw -> t2 -> A
  float* bufH  = (float*)carve((size_t)N * 128 * 4);  // h1 -> h2
  float* bufB  = (float*)carve((size_t)N * 128 * 4);  // B
  int*   cnt   = (int*)carve((size_t)N * 4);
  int*   fill  = (int*)carve((size_t)N * 4);
  int*   rowptr= (int*)carve((size_t)(N + 1) * 4);
  float* dinv  = (float*)carve((size_t)N * 4);
  int*   csr   = (int*)carve((size_t)E * 4);
  (void)ws_size; (void)n_in; (void)out_size;

  hipMemsetAsync(cnt, 0, (size_t)N * 4, stream);
  hipMemsetAsync(fill, 0, (size_t)N * 4, stream);
  count_dst_k<<<(E + 255) / 256, 256, 0, stream>>>(dst, cnt, E);
  scan_k<<<1, 1024, 0, stream>>>(cnt, rowptr, dinv, N);
  fill_csr_k<<<(E + 255) / 256, 256, 0, stream>>>(src, dst, rowptr, fill, csr, E);

  int gb = (N + 63) / 64;
  int ab = (N + 3) / 4;
  int eb = (E + 3) / 4;

  // layer 1
  gemm128_k<<<gb, 256, 0, stream>>>(x, W1, nullptr, bufX, N);
  agg_bn_relu_k<<<ab, 256, 0, stream>>>(bufX, rowptr, csr, dinv, b1, g1, be1, m1, v1, bufH, N);
  // layer 2
  gemm128_k<<<gb, 256, 0, stream>>>(bufH, W2, nullptr, bufX, N);
  agg_bn_relu_k<<<ab, 256, 0, stream>>>(bufX, rowptr, csr, dinv, b2, g2, be2, m2, v2, bufH, N);
  // edge predictor: A = h2 @ epW1[:128] + epb1 ; B = h2 @ epW1[128:]
  gemm128_k<<<gb, 256, 0, stream>>>(bufH, epW1, epb1, bufX, N);
  gemm128_k<<<gb, 256, 0, stream>>>(bufH, epW1 + 128 * 128, nullptr, bufB, N);
  // per-edge MLP + sigmoid
  edge_mlp_k<<<eb, 256, 0, stream>>>(bufX, bufB, src, dst, epW2, epb2, (float*)d_out, E);
}

// Round 2
// 581.305 us; speedup vs baseline: 1.1569x; 1.1569x over previous
//
#include <hip/hip_runtime.h>
#include <math.h>

#define BN_EPS 1e-5f

typedef unsigned short u16;
typedef unsigned int u32;

__device__ __forceinline__ float bf2f(u16 b) {
  return __uint_as_float(((u32)b) << 16);
}
__device__ __forceinline__ u16 f2bf(float f) {
  u32 u = __float_as_uint(f);
  u32 r = (u + 0x7fffu + ((u >> 16) & 1u)) >> 16;   // RNE
  return (u16)r;
}
__device__ __forceinline__ float2 bfx2(u32 p) {
  return make_float2(bf2f((u16)(p & 0xffffu)), bf2f((u16)(p >> 16)));
}
__device__ __forceinline__ u32 packbf2(float x, float y) {
  return (u32)f2bf(x) | ((u32)f2bf(y) << 16);
}

// ---------------- CSR build ----------------
__global__ void count_dst_k(const int* __restrict__ dst, int* __restrict__ cnt, int E) {
  int i = blockIdx.x * blockDim.x + threadIdx.x;
  if (i < E) atomicAdd(&cnt[dst[i]], 1);
}

__global__ __launch_bounds__(1024) void scan_k(const int* __restrict__ cnt,
                                               int* __restrict__ rowptr,
                                               float* __restrict__ dinv, int n) {
  __shared__ int part[1024];
  int tid = threadIdx.x;
  int chunk = (n + 1023) / 1024;
  int beg = tid * chunk; if (beg > n) beg = n;
  int end = beg + chunk; if (end > n) end = n;
  int s = 0;
  for (int i = beg; i < end; ++i) s += cnt[i];
  part[tid] = s;
  __syncthreads();
  for (int o = 1; o < 1024; o <<= 1) {
    int v = (tid >= o) ? part[tid - o] : 0;
    __syncthreads();
    part[tid] += v;
    __syncthreads();
  }
  int run = (tid == 0) ? 0 : part[tid - 1];
  for (int i = beg; i < end; ++i) {
    int c = cnt[i];
    rowptr[i] = run;
    run += c;
    dinv[i] = rsqrtf((float)(c + 1));   // deg = in-degree + self-loop
  }
  if (tid == 1023) rowptr[n] = part[1023];
}

__global__ void fill_csr_k(const int* __restrict__ src, const int* __restrict__ dst,
                           const int* __restrict__ rowptr, int* __restrict__ fill,
                           int* __restrict__ csr_src, int E) {
  int i = blockIdx.x * blockDim.x + threadIdx.x;
  if (i < E) {
    int d = dst[i];
    int p = rowptr[d] + atomicAdd(&fill[d], 1);
    csr_src[p] = src[i];
  }
}

// ---- GEMM: Y_bf16[M,128] = (X[M,128] @ W[128,128] (+bias)) (* dinv[row]) ----
// 64 rows/block, 256 threads. LDS: Xs 32KB + Ws(half-K) 32KB = 64KB.
template<bool BF16IN, bool SCALE, bool BIAS>
__global__ __launch_bounds__(256) void gemm128_k(const void* __restrict__ Xv,
                                                 const float* __restrict__ W,
                                                 const float* __restrict__ bias,
                                                 const float* __restrict__ dinv,
                                                 u16* __restrict__ Y, int M) {
  __shared__ float Xs[64][128];
  __shared__ float Ws[64][128];
  int tid = threadIdx.x;
  int row0 = blockIdx.x * 64;
  // stage X tile: 2048 float4-equivalents, 8 per thread
  for (int i = tid; i < 64 * 32; i += 256) {
    int r = i >> 5, c4 = i & 31;
    int gr = row0 + r;
    float4 v = make_float4(0.f, 0.f, 0.f, 0.f);
    if (gr < M) {
      if (BF16IN) {
        uint2 p = ((const uint2*)Xv)[(size_t)gr * 32 + c4];
        float2 lo = bfx2(p.x), hi = bfx2(p.y);
        v = make_float4(lo.x, lo.y, hi.x, hi.y);
      } else {
        v = ((const float4*)Xv)[(size_t)gr * 32 + c4];
      }
    }
    ((float4*)&Xs[0][0])[i] = v;
  }
  int tx = tid & 31, ty = tid >> 5;
  float4 acc[8];
  #pragma unroll
  for (int r = 0; r < 8; ++r) acc[r] = make_float4(0.f, 0.f, 0.f, 0.f);
  for (int kh = 0; kh < 2; ++kh) {
    __syncthreads();
    for (int i = tid; i < 64 * 32; i += 256)
      ((float4*)&Ws[0][0])[i] = ((const float4*)W)[kh * 2048 + i];
    __syncthreads();
    #pragma unroll 4
    for (int k = 0; k < 64; ++k) {
      float4 b = *(const float4*)&Ws[k][tx * 4];
      #pragma unroll
      for (int r = 0; r < 8; ++r) {
        float a = Xs[ty * 8 + r][kh * 64 + k];
        acc[r].x = fmaf(a, b.x, acc[r].x);
        acc[r].y = fmaf(a, b.y, acc[r].y);
        acc[r].z = fmaf(a, b.z, acc[r].z);
        acc[r].w = fmaf(a, b.w, acc[r].w);
      }
    }
  }
  float4 bv = make_float4(0.f, 0.f, 0.f, 0.f);
  if (BIAS) bv = *(const float4*)&bias[tx * 4];
  #pragma unroll
  for (int r = 0; r < 8; ++r) {
    int gr = row0 + ty * 8 + r;
    if (gr < M) {
      float4 o = acc[r];
      if (BIAS) { o.x += bv.x; o.y += bv.y; o.z += bv.z; o.w += bv.w; }
      if (SCALE) {
        float s = dinv[gr];
        o.x *= s; o.y *= s; o.z *= s; o.w *= s;
      }
      ushort4 pk;
      pk.x = f2bf(o.x); pk.y = f2bf(o.y); pk.z = f2bf(o.z); pk.w = f2bf(o.w);
      ((ushort4*)Y)[(size_t)gr * 32 + tx] = pk;
    }
  }
}

// --- per-node gather aggregate + bias + BN(eval) + ReLU (bf16 in/out) ---
// XW rows are pre-scaled by dinv[row]; out[d] = dinv[d]*(sum XW'[s] + XW'[d])
__global__ __launch_bounds__(256) void agg_bn_relu_k(const u32* __restrict__ XW,
    const int* __restrict__ rowptr, const int* __restrict__ csr_src,
    const float* __restrict__ dinv,
    const float* __restrict__ bb, const float* __restrict__ g,
    const float* __restrict__ be, const float* __restrict__ mm,
    const float* __restrict__ vv,
    u32* __restrict__ H, int n) {
  int wid = (blockIdx.x * 256 + threadIdx.x) >> 6;
  if (wid >= n) return;
  int lane = threadIdx.x & 63;
  float accx = 0.f, accy = 0.f;
  int beg = rowptr[wid], end = rowptr[wid + 1];
  int i = beg;
  for (; i + 1 < end; i += 2) {
    int s0 = csr_src[i];
    int s1 = csr_src[i + 1];
    u32 p0 = XW[(size_t)s0 * 64 + lane];
    u32 p1 = XW[(size_t)s1 * 64 + lane];
    float2 v0 = bfx2(p0), v1 = bfx2(p1);
    accx += v0.x + v1.x;
    accy += v0.y + v1.y;
  }
  if (i < end) {
    float2 v = bfx2(XW[(size_t)csr_src[i] * 64 + lane]);
    accx += v.x; accy += v.y;
  }
  float2 self = bfx2(XW[(size_t)wid * 64 + lane]);
  accx += self.x; accy += self.y;
  float dn = dinv[wid];
  accx *= dn; accy *= dn;
  int c = lane * 2;
  float s0 = g[c]     * rsqrtf(vv[c]     + BN_EPS);
  float s1 = g[c + 1] * rsqrtf(vv[c + 1] + BN_EPS);
  float o0 = (accx + bb[c]     - mm[c])     * s0 + be[c];
  float o1 = (accy + bb[c + 1] - mm[c + 1]) * s1 + be[c + 1];
  o0 = fmaxf(o0, 0.f);
  o1 = fmaxf(o1, 0.f);
  H[(size_t)wid * 64 + lane] = packbf2(o0, o1);
}

// ------ edge MLP: sigmoid(relu(A[s]+B[d]) . w2 + b2), A/B bf16 ------
__global__ __launch_bounds__(256) void edge_mlp_k(const u32* __restrict__ A,
    const u32* __restrict__ B, const int* __restrict__ src,
    const int* __restrict__ dst, const float* __restrict__ w2,
    const float* __restrict__ b2, float* __restrict__ out, int E) {
  int e = (blockIdx.x * 256 + threadIdx.x) >> 6;
  if (e >= E) return;
  int lane = threadIdx.x & 63;
  int s = src[e], d = dst[e];
  float2 a = bfx2(A[(size_t)s * 64 + lane]);
  float2 b = bfx2(B[(size_t)d * 64 + lane]);
  float2 w = ((const float2*)w2)[lane];
  float h0 = fmaxf(a.x + b.x, 0.f);
  float h1 = fmaxf(a.y + b.y, 0.f);
  float p = fmaf(h0, w.x, h1 * w.y);
  #pragma unroll
  for (int o = 32; o > 0; o >>= 1) p += __shfl_xor(p, o);
  if (lane == 0) {
    float z = p + b2[0];
    out[e] = 1.f / (1.f + expf(-z));
  }
}

extern "C" void kernel_launch(void* const* d_in, const int* in_sizes, int n_in,
                              void* d_out, int out_size, void* d_ws, size_t ws_size,
                              hipStream_t stream) {
  const float* x    = (const float*)d_in[0];
  const int*   ei   = (const int*)d_in[1];
  const float* W1   = (const float*)d_in[2];
  const float* b1   = (const float*)d_in[3];
  const float* g1   = (const float*)d_in[4];
  const float* be1  = (const float*)d_in[5];
  const float* m1   = (const float*)d_in[6];
  const float* v1   = (const float*)d_in[7];
  const float* W2   = (const float*)d_in[8];
  const float* b2   = (const float*)d_in[9];
  const float* g2   = (const float*)d_in[10];
  const float* be2  = (const float*)d_in[11];
  const float* m2   = (const float*)d_in[12];
  const float* v2   = (const float*)d_in[13];
  const float* epW1 = (const float*)d_in[14];
  const float* epb1 = (const float*)d_in[15];
  const float* epW2 = (const float*)d_in[16];
  const float* epb2 = (const float*)d_in[17];

  int N = in_sizes[0] / 128;
  int E = in_sizes[1] / 2;
  const int* src = ei;
  const int* dst = ei + E;

  char* w = (char*)d_ws;
  size_t off = 0;
  auto carve = [&](size_t bytes) {
    void* p = w + off;
    off = (off + bytes + 255) & ~(size_t)255;
    return p;
  };
  u16* bufX  = (u16*)carve((size_t)N * 128 * 2);  // xw' -> t2' -> A
  u16* bufH  = (u16*)carve((size_t)N * 128 * 2);  // h1 -> h2
  u16* bufB  = (u16*)carve((size_t)N * 128 * 2);  // B
  int*   cnt   = (int*)carve((size_t)N * 4);
  int*   fill  = (int*)carve((size_t)N * 4);
  int*   rowptr= (int*)carve((size_t)(N + 1) * 4);
  float* dinv  = (float*)carve((size_t)N * 4);
  int*   csr   = (int*)carve((size_t)E * 4);
  (void)ws_size; (void)n_in; (void)out_size;

  hipMemsetAsync(cnt, 0, (size_t)N * 4, stream);
  hipMemsetAsync(fill, 0, (size_t)N * 4, stream);
  count_dst_k<<<(E + 255) / 256, 256, 0, stream>>>(dst, cnt, E);
  scan_k<<<1, 1024, 0, stream>>>(cnt, rowptr, dinv, N);
  fill_csr_k<<<(E + 255) / 256, 256, 0, stream>>>(src, dst, rowptr, fill, csr, E);

  int gb = (N + 63) / 64;
  int ab = (N + 3) / 4;
  int eb = (E + 3) / 4;

  // layer 1: XW' = dinv * (x @ W1)
  gemm128_k<false, true, false><<<gb, 256, 0, stream>>>(x, W1, nullptr, dinv, bufX, N);
  agg_bn_relu_k<<<ab, 256, 0, stream>>>((const u32*)bufX, rowptr, csr, dinv,
                                        b1, g1, be1, m1, v1, (u32*)bufH, N);
  // layer 2
  gemm128_k<true, true, false><<<gb, 256, 0, stream>>>(bufH, W2, nullptr, dinv, bufX, N);
  agg_bn_relu_k<<<ab, 256, 0, stream>>>((const u32*)bufX, rowptr, csr, dinv,
                                        b2, g2, be2, m2, v2, (u32*)bufH, N);
  // edge predictor: A = h2 @ epW1[:128] + epb1 ; B = h2 @ epW1[128:]
  gemm128_k<true, false, true><<<gb, 256, 0, stream>>>(bufH, epW1, epb1, nullptr, bufX, N);
  gemm128_k<true, false, false><<<gb, 256, 0, stream>>>(bufH, epW1 + 128 * 128, nullptr, nullptr, bufB, N);
  // per-edge MLP + sigmoid
  edge_mlp_k<<<eb, 256, 0, stream>>>((const u32*)bufX, (const u32*)bufB, src, dst,
                                     epW2, epb2, (float*)d_out, E);
}

// Round 3
// 469.048 us; speedup vs baseline: 1.4338x; 1.2393x over previous
//
#include <hip/hip_runtime.h>
#include <math.h>

#define BN_EPS 1e-5f

typedef unsigned short u16;
typedef unsigned int u32;

__device__ __forceinline__ float bf2f(u16 b) {
  return __uint_as_float(((u32)b) << 16);
}
__device__ __forceinline__ u16 f2bf(float f) {
  u32 u = __float_as_uint(f);
  u32 r = (u + 0x7fffu + ((u >> 16) & 1u)) >> 16;   // RNE
  return (u16)r;
}
__device__ __forceinline__ float2 bfx2(u32 p) {
  return make_float2(bf2f((u16)(p & 0xffffu)), bf2f((u16)(p >> 16)));
}
__device__ __forceinline__ u32 packbf2(float x, float y) {
  return (u32)f2bf(x) | ((u32)f2bf(y) << 16);
}
__device__ __forceinline__ float lo_bf(u32 p) { return __uint_as_float(p << 16); }
__device__ __forceinline__ float hi_bf(u32 p) { return __uint_as_float(p & 0xffff0000u); }

// ---------------- CSR build ----------------
__global__ void count_dst_k(const int* __restrict__ dst, int* __restrict__ cnt, int E) {
  int i = blockIdx.x * blockDim.x + threadIdx.x;
  if (i < E) atomicAdd(&cnt[dst[i]], 1);
}

__global__ __launch_bounds__(1024) void scan_k(const int* __restrict__ cnt,
                                               int* __restrict__ rowptr,
                                               float* __restrict__ dinv, int n) {
  __shared__ int part[1024];
  int tid = threadIdx.x;
  int chunk = (n + 1023) / 1024;
  int beg = tid * chunk; if (beg > n) beg = n;
  int end = beg + chunk; if (end > n) end = n;
  int s = 0;
  for (int i = beg; i < end; ++i) s += cnt[i];
  part[tid] = s;
  __syncthreads();
  for (int o = 1; o < 1024; o <<= 1) {
    int v = (tid >= o) ? part[tid - o] : 0;
    __syncthreads();
    part[tid] += v;
    __syncthreads();
  }
  int run = (tid == 0) ? 0 : part[tid - 1];
  for (int i = beg; i < end; ++i) {
    int c = cnt[i];
    rowptr[i] = run;
    run += c;
    dinv[i] = rsqrtf((float)(c + 1));   // deg = in-degree + self-loop
  }
  if (tid == 1023) rowptr[n] = part[1023];
}

__global__ void fill_csr_k(const int* __restrict__ src, const int* __restrict__ dst,
                           const int* __restrict__ rowptr, int* __restrict__ fill,
                           int* __restrict__ csr_src, int* __restrict__ csr_dst,
                           int* __restrict__ csr_eid, int E) {
  int i = blockIdx.x * blockDim.x + threadIdx.x;
  if (i < E) {
    int d = dst[i];
    int p = rowptr[d] + atomicAdd(&fill[d], 1);
    csr_src[p] = src[i];
    csr_dst[p] = d;
    csr_eid[p] = i;
  }
}

// ---- GEMM: Y_bf16[M,128] = (X[M,128] @ W[128,128] (+bias)) (* dinv[row]) ----
template<bool BF16IN, bool SCALE, bool BIAS>
__global__ __launch_bounds__(256) void gemm128_k(const void* __restrict__ Xv,
                                                 const float* __restrict__ W,
                                                 const float* __restrict__ bias,
                                                 const float* __restrict__ dinv,
                                                 u16* __restrict__ Y, int M) {
  __shared__ float Xs[64][128];
  __shared__ float Ws[64][128];
  int tid = threadIdx.x;
  int row0 = blockIdx.x * 64;
  for (int i = tid; i < 64 * 32; i += 256) {
    int r = i >> 5, c4 = i & 31;
    int gr = row0 + r;
    float4 v = make_float4(0.f, 0.f, 0.f, 0.f);
    if (gr < M) {
      if (BF16IN) {
        uint2 p = ((const uint2*)Xv)[(size_t)gr * 32 + c4];
        float2 lo = bfx2(p.x), hi = bfx2(p.y);
        v = make_float4(lo.x, lo.y, hi.x, hi.y);
      } else {
        v = ((const float4*)Xv)[(size_t)gr * 32 + c4];
      }
    }
    ((float4*)&Xs[0][0])[i] = v;
  }
  int tx = tid & 31, ty = tid >> 5;
  float4 acc[8];
  #pragma unroll
  for (int r = 0; r < 8; ++r) acc[r] = make_float4(0.f, 0.f, 0.f, 0.f);
  for (int kh = 0; kh < 2; ++kh) {
    __syncthreads();
    for (int i = tid; i < 64 * 32; i += 256)
      ((float4*)&Ws[0][0])[i] = ((const float4*)W)[kh * 2048 + i];
    __syncthreads();
    #pragma unroll 4
    for (int k = 0; k < 64; ++k) {
      float4 b = *(const float4*)&Ws[k][tx * 4];
      #pragma unroll
      for (int r = 0; r < 8; ++r) {
        float a = Xs[ty * 8 + r][kh * 64 + k];
        acc[r].x = fmaf(a, b.x, acc[r].x);
        acc[r].y = fmaf(a, b.y, acc[r].y);
        acc[r].z = fmaf(a, b.z, acc[r].z);
        acc[r].w = fmaf(a, b.w, acc[r].w);
      }
    }
  }
  float4 bv = make_float4(0.f, 0.f, 0.f, 0.f);
  if (BIAS) bv = *(const float4*)&bias[tx * 4];
  #pragma unroll
  for (int r = 0; r < 8; ++r) {
    int gr = row0 + ty * 8 + r;
    if (gr < M) {
      float4 o = acc[r];
      if (BIAS) { o.x += bv.x; o.y += bv.y; o.z += bv.z; o.w += bv.w; }
      if (SCALE) {
        float s = dinv[gr];
        o.x *= s; o.y *= s; o.z *= s; o.w *= s;
      }
      ushort4 pk;
      pk.x = f2bf(o.x); pk.y = f2bf(o.y); pk.z = f2bf(o.z); pk.w = f2bf(o.w);
      ((ushort4*)Y)[(size_t)gr * 32 + tx] = pk;
    }
  }
}

// --- per-node gather aggregate + bias + BN(eval) + ReLU (bf16 in/out) ---
// XW rows pre-scaled by dinv[row]; out[d] = dinv[d]*(sum XW'[s] + XW'[d])
// wave per node, unroll-4 to keep 4 gathers in flight
__global__ __launch_bounds__(256) void agg_bn_relu_k(const u32* __restrict__ XW,
    const int* __restrict__ rowptr, const int* __restrict__ csr_src,
    const float* __restrict__ dinv,
    const float* __restrict__ bb, const float* __restrict__ g,
    const float* __restrict__ be, const float* __restrict__ mm,
    const float* __restrict__ vv,
    u32* __restrict__ H, int n) {
  int wid = (blockIdx.x * 256 + threadIdx.x) >> 6;
  if (wid >= n) return;
  int lane = threadIdx.x & 63;
  float ax = 0.f, ay = 0.f;
  int beg = rowptr[wid], end = rowptr[wid + 1];
  int i = beg;
  for (; i + 3 < end; i += 4) {
    int s0 = csr_src[i];
    int s1 = csr_src[i + 1];
    int s2 = csr_src[i + 2];
    int s3 = csr_src[i + 3];
    u32 p0 = XW[(size_t)s0 * 64 + lane];
    u32 p1 = XW[(size_t)s1 * 64 + lane];
    u32 p2 = XW[(size_t)s2 * 64 + lane];
    u32 p3 = XW[(size_t)s3 * 64 + lane];
    ax += lo_bf(p0); ay += hi_bf(p0);
    ax += lo_bf(p1); ay += hi_bf(p1);
    ax += lo_bf(p2); ay += hi_bf(p2);
    ax += lo_bf(p3); ay += hi_bf(p3);
  }
  for (; i < end; ++i) {
    u32 p = XW[(size_t)csr_src[i] * 64 + lane];
    ax += lo_bf(p); ay += hi_bf(p);
  }
  u32 ps = XW[(size_t)wid * 64 + lane];
  ax += lo_bf(ps); ay += hi_bf(ps);
  float dn = dinv[wid];
  ax *= dn; ay *= dn;
  int c = lane * 2;
  float s0 = g[c]     * rsqrtf(vv[c]     + BN_EPS);
  float s1 = g[c + 1] * rsqrtf(vv[c + 1] + BN_EPS);
  float o0 = (ax + bb[c]     - mm[c])     * s0 + be[c];
  float o1 = (ay + bb[c + 1] - mm[c + 1]) * s1 + be[c + 1];
  o0 = fmaxf(o0, 0.f);
  o1 = fmaxf(o1, 0.f);
  H[(size_t)wid * 64 + lane] = packbf2(o0, o1);
}

// ------ edge MLP: sigmoid(relu(A[s]+B[d]) . w2 + b2), thread per edge, CSR order ------
__global__ __launch_bounds__(256) void edge_mlp_k(const u32* __restrict__ A,
    const u32* __restrict__ B, const int* __restrict__ csr_src,
    const int* __restrict__ csr_dst, const int* __restrict__ csr_eid,
    const float* __restrict__ w2, const float* __restrict__ b2,
    float* __restrict__ out, int E) {
  int t = blockIdx.x * 256 + threadIdx.x;
  if (t >= E) return;
  int s = csr_src[t];
  int d = csr_dst[t];
  int e = csr_eid[t];
  const uint4* Ar = (const uint4*)(A + (size_t)s * 64);
  const uint4* Br = (const uint4*)(B + (size_t)d * 64);
  float acc = 0.f;
  #pragma unroll
  for (int j = 0; j < 16; ++j) {
    uint4 pa = Ar[j];
    uint4 pb = Br[j];
    float4 wa = ((const float4*)w2)[2 * j];
    float4 wb = ((const float4*)w2)[2 * j + 1];
    float h;
    h = fmaxf(lo_bf(pa.x) + lo_bf(pb.x), 0.f); acc = fmaf(h, wa.x, acc);
    h = fmaxf(hi_bf(pa.x) + hi_bf(pb.x), 0.f); acc = fmaf(h, wa.y, acc);
    h = fmaxf(lo_bf(pa.y) + lo_bf(pb.y), 0.f); acc = fmaf(h, wa.z, acc);
    h = fmaxf(hi_bf(pa.y) + hi_bf(pb.y), 0.f); acc = fmaf(h, wa.w, acc);
    h = fmaxf(lo_bf(pa.z) + lo_bf(pb.z), 0.f); acc = fmaf(h, wb.x, acc);
    h = fmaxf(hi_bf(pa.z) + hi_bf(pb.z), 0.f); acc = fmaf(h, wb.y, acc);
    h = fmaxf(lo_bf(pa.w) + lo_bf(pb.w), 0.f); acc = fmaf(h, wb.z, acc);
    h = fmaxf(hi_bf(pa.w) + hi_bf(pb.w), 0.f); acc = fmaf(h, wb.w, acc);
  }
  float z = acc + b2[0];
  out[e] = 1.f / (1.f + expf(-z));
}

extern "C" void kernel_launch(void* const* d_in, const int* in_sizes, int n_in,
                              void* d_out, int out_size, void* d_ws, size_t ws_size,
                              hipStream_t stream) {
  const float* x    = (const float*)d_in[0];
  const int*   ei   = (const int*)d_in[1];
  const float* W1   = (const float*)d_in[2];
  const float* b1   = (const float*)d_in[3];
  const float* g1   = (const float*)d_in[4];
  const float* be1  = (const float*)d_in[5];
  const float* m1   = (const float*)d_in[6];
  const float* v1   = (const float*)d_in[7];
  const float* W2   = (const float*)d_in[8];
  const float* b2   = (const float*)d_in[9];
  const float* g2   = (const float*)d_in[10];
  const float* be2  = (const float*)d_in[11];
  const float* m2   = (const float*)d_in[12];
  const float* v2   = (const float*)d_in[13];
  const float* epW1 = (const float*)d_in[14];
  const float* epb1 = (const float*)d_in[15];
  const float* epW2 = (const float*)d_in[16];
  const float* epb2 = (const float*)d_in[17];

  int N = in_sizes[0] / 128;
  int E = in_sizes[1] / 2;
  const int* src = ei;
  const int* dst = ei + E;

  char* w = (char*)d_ws;
  size_t off = 0;
  auto carve = [&](size_t bytes) {
    void* p = w + off;
    off = (off + bytes + 255) & ~(size_t)255;
    return p;
  };
  u16* bufX  = (u16*)carve((size_t)N * 128 * 2);  // xw' -> t2' -> A
  u16* bufH  = (u16*)carve((size_t)N * 128 * 2);  // h1 -> h2
  u16* bufB  = (u16*)carve((size_t)N * 128 * 2);  // B
  int*   cnt   = (int*)carve((size_t)N * 4);
  int*   fill  = (int*)carve((size_t)N * 4);
  int*   rowptr= (int*)carve((size_t)(N + 1) * 4);
  float* dinv  = (float*)carve((size_t)N * 4);
  int*   csr   = (int*)carve((size_t)E * 4);
  int*   csrD  = (int*)carve((size_t)E * 4);
  int*   csrE  = (int*)carve((size_t)E * 4);
  (void)ws_size; (void)n_in; (void)out_size;

  hipMemsetAsync(cnt, 0, (size_t)N * 4, stream);
  hipMemsetAsync(fill, 0, (size_t)N * 4, stream);
  count_dst_k<<<(E + 255) / 256, 256, 0, stream>>>(dst, cnt, E);
  scan_k<<<1, 1024, 0, stream>>>(cnt, rowptr, dinv, N);
  fill_csr_k<<<(E + 255) / 256, 256, 0, stream>>>(src, dst, rowptr, fill, csr, csrD, csrE, E);

  int gb = (N + 63) / 64;
  int ab = (N + 3) / 4;

  // layer 1: XW' = dinv * (x @ W1)
  gemm128_k<false, true, false><<<gb, 256, 0, stream>>>(x, W1, nullptr, dinv, bufX, N);
  agg_bn_relu_k<<<ab, 256, 0, stream>>>((const u32*)bufX, rowptr, csr, dinv,
                                        b1, g1, be1, m1, v1, (u32*)bufH, N);
  // layer 2
  gemm128_k<true, true, false><<<gb, 256, 0, stream>>>(bufH, W2, nullptr, dinv, bufX, N);
  agg_bn_relu_k<<<ab, 256, 0, stream>>>((const u32*)bufX, rowptr, csr, dinv,
                                        b2, g2, be2, m2, v2, (u32*)bufH, N);
  // edge predictor: A = h2 @ epW1[:128] + epb1 ; B = h2 @ epW1[128:]
  gemm128_k<true, false, true><<<gb, 256, 0, stream>>>(bufH, epW1, epb1, nullptr, bufX, N);
  gemm128_k<true, false, false><<<gb, 256, 0, stream>>>(bufH, epW1 + 128 * 128, nullptr, nullptr, bufB, N);
  // per-edge MLP + sigmoid (CSR order: B-row gathers L1-resident)
  edge_mlp_k<<<(E + 255) / 256, 256, 0, stream>>>((const u32*)bufX, (const u32*)bufB,
                                                  csr, csrD, csrE, epW2, epb2,
                                                  (float*)d_out, E);
}

// Round 4
// 373.828 us; speedup vs baseline: 1.7990x; 1.2547x over previous
//
#include <hip/hip_runtime.h>
#include <math.h>

#define BN_EPS 1e-5f

typedef unsigned short u16;
typedef unsigned int u32;

__device__ __forceinline__ float bf2f(u16 b) {
  return __uint_as_float(((u32)b) << 16);
}
__device__ __forceinline__ u16 f2bf(float f) {
  u32 u = __float_as_uint(f);
  u32 r = (u + 0x7fffu + ((u >> 16) & 1u)) >> 16;   // RNE
  return (u16)r;
}
__device__ __forceinline__ float2 bfx2(u32 p) {
  return make_float2(bf2f((u16)(p & 0xffffu)), bf2f((u16)(p >> 16)));
}
__device__ __forceinline__ u32 packbf2(float x, float y) {
  return (u32)f2bf(x) | ((u32)f2bf(y) << 16);
}
__device__ __forceinline__ float lo_bf(u32 p) { return __uint_as_float(p << 16); }
__device__ __forceinline__ float hi_bf(u32 p) { return __uint_as_float(p & 0xffff0000u); }

// ---------------- CSR build ----------------
__global__ void count_dst_k(const int* __restrict__ dst, int* __restrict__ cnt, int E) {
  int i = blockIdx.x * blockDim.x + threadIdx.x;
  if (i < E) atomicAdd(&cnt[dst[i]], 1);
}

// phase 1: per-block (256 elems) sums
__global__ __launch_bounds__(256) void blocksum_k(const int* __restrict__ cnt,
                                                  int* __restrict__ bsum, int n) {
  __shared__ int red[256];
  int tid = threadIdx.x;
  int i = blockIdx.x * 256 + tid;
  int v = (i < n) ? cnt[i] : 0;
  red[tid] = v;
  __syncthreads();
  for (int o = 128; o > 0; o >>= 1) {
    if (tid < o) red[tid] += red[tid + o];
    __syncthreads();
  }
  if (tid == 0) bsum[blockIdx.x] = red[0];
}

// phase 2: exclusive scan of block sums (nb <= 1024), single block
__global__ __launch_bounds__(1024) void scan_bsum_k(int* __restrict__ bsum, int nb) {
  __shared__ int part[1024];
  int tid = threadIdx.x;
  int v = (tid < nb) ? bsum[tid] : 0;
  part[tid] = v;
  __syncthreads();
  for (int o = 1; o < 1024; o <<= 1) {
    int t = (tid >= o) ? part[tid - o] : 0;
    __syncthreads();
    part[tid] += t;
    __syncthreads();
  }
  if (tid < nb) bsum[tid] = part[tid] - v;   // exclusive
}

// phase 3: in-block exclusive scan + block offset -> rowptr, dinv
__global__ __launch_bounds__(256) void scan_final_k(const int* __restrict__ cnt,
                                                    const int* __restrict__ bsum,
                                                    int* __restrict__ rowptr,
                                                    float* __restrict__ dinv, int n) {
  __shared__ int part[256];
  int tid = threadIdx.x;
  int i = blockIdx.x * 256 + tid;
  int v = (i < n) ? cnt[i] : 0;
  part[tid] = v;
  __syncthreads();
  for (int o = 1; o < 256; o <<= 1) {
    int t = (tid >= o) ? part[tid - o] : 0;
    __syncthreads();
    part[tid] += t;
    __syncthreads();
  }
  if (i < n) {
    int excl = part[tid] - v + bsum[blockIdx.x];
    rowptr[i] = excl;
    dinv[i] = rsqrtf((float)(v + 1));   // deg = in-degree + self-loop
    if (i == n - 1) rowptr[n] = excl + v;
  }
}

__global__ void fill_csr_k(const int* __restrict__ src, const int* __restrict__ dst,
                           const int* __restrict__ rowptr, int* __restrict__ fill,
                           int* __restrict__ csr_src, int* __restrict__ csr_dst,
                           int* __restrict__ csr_eid, int E) {
  int i = blockIdx.x * blockDim.x + threadIdx.x;
  if (i < E) {
    int d = dst[i];
    int p = rowptr[d] + atomicAdd(&fill[d], 1);
    csr_src[p] = src[i];
    csr_dst[p] = d;
    csr_eid[p] = i;
  }
}

// ---- GEMM: Y_bf16[M,128] = (X[M,128] @ W[128,128] (+bias)) (* dinv[row]) ----
template<bool BF16IN, bool SCALE, bool BIAS>
__global__ __launch_bounds__(256) void gemm128_k(const void* __restrict__ Xv,
                                                 const float* __restrict__ W,
                                                 const float* __restrict__ bias,
                                                 const float* __restrict__ dinv,
                                                 u16* __restrict__ Y, int M) {
  __shared__ float Xs[64][128];
  __shared__ float Ws[64][128];
  int tid = threadIdx.x;
  int row0 = blockIdx.x * 64;
  for (int i = tid; i < 64 * 32; i += 256) {
    int r = i >> 5, c4 = i & 31;
    int gr = row0 + r;
    float4 v = make_float4(0.f, 0.f, 0.f, 0.f);
    if (gr < M) {
      if (BF16IN) {
        uint2 p = ((const uint2*)Xv)[(size_t)gr * 32 + c4];
        float2 lo = bfx2(p.x), hi = bfx2(p.y);
        v = make_float4(lo.x, lo.y, hi.x, hi.y);
      } else {
        v = ((const float4*)Xv)[(size_t)gr * 32 + c4];
      }
    }
    ((float4*)&Xs[0][0])[i] = v;
  }
  int tx = tid & 31, ty = tid >> 5;
  float4 acc[8];
  #pragma unroll
  for (int r = 0; r < 8; ++r) acc[r] = make_float4(0.f, 0.f, 0.f, 0.f);
  for (int kh = 0; kh < 2; ++kh) {
    __syncthreads();
    for (int i = tid; i < 64 * 32; i += 256)
      ((float4*)&Ws[0][0])[i] = ((const float4*)W)[kh * 2048 + i];
    __syncthreads();
    #pragma unroll 4
    for (int k = 0; k < 64; ++k) {
      float4 b = *(const float4*)&Ws[k][tx * 4];
      #pragma unroll
      for (int r = 0; r < 8; ++r) {
        float a = Xs[ty * 8 + r][kh * 64 + k];
        acc[r].x = fmaf(a, b.x, acc[r].x);
        acc[r].y = fmaf(a, b.y, acc[r].y);
        acc[r].z = fmaf(a, b.z, acc[r].z);
        acc[r].w = fmaf(a, b.w, acc[r].w);
      }
    }
  }
  float4 bv = make_float4(0.f, 0.f, 0.f, 0.f);
  if (BIAS) bv = *(const float4*)&bias[tx * 4];
  #pragma unroll
  for (int r = 0; r < 8; ++r) {
    int gr = row0 + ty * 8 + r;
    if (gr < M) {
      float4 o = acc[r];
      if (BIAS) { o.x += bv.x; o.y += bv.y; o.z += bv.z; o.w += bv.w; }
      if (SCALE) {
        float s = dinv[gr];
        o.x *= s; o.y *= s; o.z *= s; o.w *= s;
      }
      ushort4 pk;
      pk.x = f2bf(o.x); pk.y = f2bf(o.y); pk.z = f2bf(o.z); pk.w = f2bf(o.w);
      ((ushort4*)Y)[(size_t)gr * 32 + tx] = pk;
    }
  }
}

// --- per-node gather aggregate + bias + BN(eval) + ReLU (bf16 in/out) ---
// XW rows pre-scaled by dinv[row]; out[d] = dinv[d]*(sum XW'[s] + XW'[d])
// wave per node, unroll-4 to keep 4 gathers in flight
__global__ __launch_bounds__(256) void agg_bn_relu_k(const u32* __restrict__ XW,
    const int* __restrict__ rowptr, const int* __restrict__ csr_src,
    const float* __restrict__ dinv,
    const float* __restrict__ bb, const float* __restrict__ g,
    const float* __restrict__ be, const float* __restrict__ mm,
    const float* __restrict__ vv,
    u32* __restrict__ H, int n) {
  int wid = (blockIdx.x * 256 + threadIdx.x) >> 6;
  if (wid >= n) return;
  int lane = threadIdx.x & 63;
  float ax = 0.f, ay = 0.f;
  int beg = rowptr[wid], end = rowptr[wid + 1];
  int i = beg;
  for (; i + 3 < end; i += 4) {
    int s0 = csr_src[i];
    int s1 = csr_src[i + 1];
    int s2 = csr_src[i + 2];
    int s3 = csr_src[i + 3];
    u32 p0 = XW[(size_t)s0 * 64 + lane];
    u32 p1 = XW[(size_t)s1 * 64 + lane];
    u32 p2 = XW[(size_t)s2 * 64 + lane];
    u32 p3 = XW[(size_t)s3 * 64 + lane];
    ax += lo_bf(p0); ay += hi_bf(p0);
    ax += lo_bf(p1); ay += hi_bf(p1);
    ax += lo_bf(p2); ay += hi_bf(p2);
    ax += lo_bf(p3); ay += hi_bf(p3);
  }
  for (; i < end; ++i) {
    u32 p = XW[(size_t)csr_src[i] * 64 + lane];
    ax += lo_bf(p); ay += hi_bf(p);
  }
  u32 ps = XW[(size_t)wid * 64 + lane];
  ax += lo_bf(ps); ay += hi_bf(ps);
  float dn = dinv[wid];
  ax *= dn; ay *= dn;
  int c = lane * 2;
  float s0 = g[c]     * rsqrtf(vv[c]     + BN_EPS);
  float s1 = g[c + 1] * rsqrtf(vv[c + 1] + BN_EPS);
  float o0 = (ax + bb[c]     - mm[c])     * s0 + be[c];
  float o1 = (ay + bb[c + 1] - mm[c + 1]) * s1 + be[c + 1];
  o0 = fmaxf(o0, 0.f);
  o1 = fmaxf(o1, 0.f);
  H[(size_t)wid * 64 + lane] = packbf2(o0, o1);
}

// ------ edge MLP: sigmoid(relu(A[s]+B[d]) . w2 + b2), thread per edge, CSR order ------
__global__ __launch_bounds__(256) void edge_mlp_k(const u32* __restrict__ A,
    const u32* __restrict__ B, const int* __restrict__ csr_src,
    const int* __restrict__ csr_dst, const int* __restrict__ csr_eid,
    const float* __restrict__ w2, const float* __restrict__ b2,
    float* __restrict__ out, int E) {
  int t = blockIdx.x * 256 + threadIdx.x;
  if (t >= E) return;
  int s = csr_src[t];
  int d = csr_dst[t];
  int e = csr_eid[t];
  const uint4* Ar = (const uint4*)(A + (size_t)s * 64);
  const uint4* Br = (const uint4*)(B + (size_t)d * 64);
  float acc = 0.f;
  #pragma unroll
  for (int j = 0; j < 16; ++j) {
    uint4 pa = Ar[j];
    uint4 pb = Br[j];
    float4 wa = ((const float4*)w2)[2 * j];
    float4 wb = ((const float4*)w2)[2 * j + 1];
    float h;
    h = fmaxf(lo_bf(pa.x) + lo_bf(pb.x), 0.f); acc = fmaf(h, wa.x, acc);
    h = fmaxf(hi_bf(pa.x) + hi_bf(pb.x), 0.f); acc = fmaf(h, wa.y, acc);
    h = fmaxf(lo_bf(pa.y) + lo_bf(pb.y), 0.f); acc = fmaf(h, wa.z, acc);
    h = fmaxf(hi_bf(pa.y) + hi_bf(pb.y), 0.f); acc = fmaf(h, wa.w, acc);
    h = fmaxf(lo_bf(pa.z) + lo_bf(pb.z), 0.f); acc = fmaf(h, wb.x, acc);
    h = fmaxf(hi_bf(pa.z) + hi_bf(pb.z), 0.f); acc = fmaf(h, wb.y, acc);
    h = fmaxf(lo_bf(pa.w) + lo_bf(pb.w), 0.f); acc = fmaf(h, wb.z, acc);
    h = fmaxf(hi_bf(pa.w) + hi_bf(pb.w), 0.f); acc = fmaf(h, wb.w, acc);
  }
  float z = acc + b2[0];
  out[e] = 1.f / (1.f + expf(-z));
}

extern "C" void kernel_launch(void* const* d_in, const int* in_sizes, int n_in,
                              void* d_out, int out_size, void* d_ws, size_t ws_size,
                              hipStream_t stream) {
  const float* x    = (const float*)d_in[0];
  const int*   ei   = (const int*)d_in[1];
  const float* W1   = (const float*)d_in[2];
  const float* b1   = (const float*)d_in[3];
  const float* g1   = (const float*)d_in[4];
  const float* be1  = (const float*)d_in[5];
  const float* m1   = (const float*)d_in[6];
  const float* v1   = (const float*)d_in[7];
  const float* W2   = (const float*)d_in[8];
  const float* b2   = (const float*)d_in[9];
  const float* g2   = (const float*)d_in[10];
  const float* be2  = (const float*)d_in[11];
  const float* m2   = (const float*)d_in[12];
  const float* v2   = (const float*)d_in[13];
  const float* epW1 = (const float*)d_in[14];
  const float* epb1 = (const float*)d_in[15];
  const float* epW2 = (const float*)d_in[16];
  const float* epb2 = (const float*)d_in[17];

  int N = in_sizes[0] / 128;
  int E = in_sizes[1] / 2;
  const int* src = ei;
  const int* dst = ei + E;

  char* w = (char*)d_ws;
  size_t off = 0;
  auto carve = [&](size_t bytes) {
    void* p = w + off;
    off = (off + bytes + 255) & ~(size_t)255;
    return p;
  };
  u16* bufX  = (u16*)carve((size_t)N * 128 * 2);  // xw' -> t2' -> A
  u16* bufH  = (u16*)carve((size_t)N * 128 * 2);  // h1 -> h2
  u16* bufB  = (u16*)carve((size_t)N * 128 * 2);  // B
  int*   cnt   = (int*)carve((size_t)N * 4);
  int*   fill  = (int*)carve((size_t)N * 4);
  int*   rowptr= (int*)carve((size_t)(N + 1) * 4);
  float* dinv  = (float*)carve((size_t)N * 4);
  int*   csr   = (int*)carve((size_t)E * 4);
  int*   csrD  = (int*)carve((size_t)E * 4);
  int*   csrE  = (int*)carve((size_t)E * 4);
  int*   bsum  = (int*)carve((size_t)1024 * 4);
  (void)ws_size; (void)n_in; (void)out_size;

  int nb = (N + 255) / 256;   // 196 for N=50000, <= 1024

  hipMemsetAsync(cnt, 0, (size_t)N * 4, stream);
  hipMemsetAsync(fill, 0, (size_t)N * 4, stream);
  count_dst_k<<<(E + 255) / 256, 256, 0, stream>>>(dst, cnt, E);
  blocksum_k<<<nb, 256, 0, stream>>>(cnt, bsum, N);
  scan_bsum_k<<<1, 1024, 0, stream>>>(bsum, nb);
  scan_final_k<<<nb, 256, 0, stream>>>(cnt, bsum, rowptr, dinv, N);
  fill_csr_k<<<(E + 255) / 256, 256, 0, stream>>>(src, dst, rowptr, fill, csr, csrD, csrE, E);

  int gb = (N + 63) / 64;
  int ab = (N + 3) / 4;

  // layer 1: XW' = dinv * (x @ W1)
  gemm128_k<false, true, false><<<gb, 256, 0, stream>>>(x, W1, nullptr, dinv, bufX, N);
  agg_bn_relu_k<<<ab, 256, 0, stream>>>((const u32*)bufX, rowptr, csr, dinv,
                                        b1, g1, be1, m1, v1, (u32*)bufH, N);
  // layer 2
  gemm128_k<true, true, false><<<gb, 256, 0, stream>>>(bufH, W2, nullptr, dinv, bufX, N);
  agg_bn_relu_k<<<ab, 256, 0, stream>>>((const u32*)bufX, rowptr, csr, dinv,
                                        b2, g2, be2, m2, v2, (u32*)bufH, N);
  // edge predictor: A = h2 @ epW1[:128] + epb1 ; B = h2 @ epW1[128:]
  gemm128_k<true, false, true><<<gb, 256, 0, stream>>>(bufH, epW1, epb1, nullptr, bufX, N);
  gemm128_k<true, false, false><<<gb, 256, 0, stream>>>(bufH, epW1 + 128 * 128, nullptr, nullptr, bufB, N);
  // per-edge MLP + sigmoid (CSR order: B-row gathers L1-resident)
  edge_mlp_k<<<(E + 255) / 256, 256, 0, stream>>>((const u32*)bufX, (const u32*)bufB,
                                                  csr, csrD, csrE, epW2, epb2,
                                                  (float*)d_out, E);
}

// Round 5
// 322.525 us; speedup vs baseline: 2.0852x; 1.1591x over previous
//
#include <hip/hip_runtime.h>
#include <math.h>

#define BN_EPS 1e-5f

typedef unsigned short u16;
typedef unsigned int u32;
typedef __attribute__((ext_vector_type(8))) short bf16x8;
typedef __attribute__((ext_vector_type(4))) float f32x4;

__device__ __forceinline__ float bf2f(u16 b) {
  return __uint_as_float(((u32)b) << 16);
}
__device__ __forceinline__ u16 f2bf(float f) {
  u32 u = __float_as_uint(f);
  u32 r = (u + 0x7fffu + ((u >> 16) & 1u)) >> 16;   // RNE
  return (u16)r;
}
__device__ __forceinline__ float2 bfx2(u32 p) {
  return make_float2(bf2f((u16)(p & 0xffffu)), bf2f((u16)(p >> 16)));
}
__device__ __forceinline__ u32 packbf2(float x, float y) {
  return (u32)f2bf(x) | ((u32)f2bf(y) << 16);
}
__device__ __forceinline__ float lo_bf(u32 p) { return __uint_as_float(p << 16); }
__device__ __forceinline__ float hi_bf(u32 p) { return __uint_as_float(p & 0xffff0000u); }

// ---------------- CSR build ----------------
__global__ void count_dst_k(const int* __restrict__ dst, int* __restrict__ cnt, int E) {
  int i = blockIdx.x * blockDim.x + threadIdx.x;
  if (i < E) atomicAdd(&cnt[dst[i]], 1);
}

__global__ __launch_bounds__(256) void blocksum_k(const int* __restrict__ cnt,
                                                  int* __restrict__ bsum, int n) {
  __shared__ int red[256];
  int tid = threadIdx.x;
  int i = blockIdx.x * 256 + tid;
  int v = (i < n) ? cnt[i] : 0;
  red[tid] = v;
  __syncthreads();
  for (int o = 128; o > 0; o >>= 1) {
    if (tid < o) red[tid] += red[tid + o];
    __syncthreads();
  }
  if (tid == 0) bsum[blockIdx.x] = red[0];
}

__global__ __launch_bounds__(1024) void scan_bsum_k(int* __restrict__ bsum, int nb) {
  __shared__ int part[1024];
  int tid = threadIdx.x;
  int v = (tid < nb) ? bsum[tid] : 0;
  part[tid] = v;
  __syncthreads();
  for (int o = 1; o < 1024; o <<= 1) {
    int t = (tid >= o) ? part[tid - o] : 0;
    __syncthreads();
    part[tid] += t;
    __syncthreads();
  }
  if (tid < nb) bsum[tid] = part[tid] - v;   // exclusive
}

__global__ __launch_bounds__(256) void scan_final_k(const int* __restrict__ cnt,
                                                    const int* __restrict__ bsum,
                                                    int* __restrict__ rowptr,
                                                    float* __restrict__ dinv, int n) {
  __shared__ int part[256];
  int tid = threadIdx.x;
  int i = blockIdx.x * 256 + tid;
  int v = (i < n) ? cnt[i] : 0;
  part[tid] = v;
  __syncthreads();
  for (int o = 1; o < 256; o <<= 1) {
    int t = (tid >= o) ? part[tid - o] : 0;
    __syncthreads();
    part[tid] += t;
    __syncthreads();
  }
  if (i < n) {
    int excl = part[tid] - v + bsum[blockIdx.x];
    rowptr[i] = excl;
    dinv[i] = rsqrtf((float)(v + 1));   // deg = in-degree + self-loop
    if (i == n - 1) rowptr[n] = excl + v;
  }
}

// one scattered 8B store per edge (src, eid); dst reconstructed separately
__global__ void fill_csr_k(const int* __restrict__ src, const int* __restrict__ dst,
                           const int* __restrict__ rowptr, int* __restrict__ fill,
                           int2* __restrict__ se, int E) {
  int i = blockIdx.x * blockDim.x + threadIdx.x;
  if (i < E) {
    int d = dst[i];
    int p = rowptr[d] + atomicAdd(&fill[d], 1);
    se[p] = make_int2(src[i], i);
  }
}

__global__ void expand_dst_k(const int* __restrict__ rowptr, int* __restrict__ csrD, int n) {
  int i = blockIdx.x * blockDim.x + threadIdx.x;
  if (i < n) {
    int b = rowptr[i], e = rowptr[i + 1];
    for (int j = b; j < e; ++j) csrD[j] = i;
  }
}

// ---- weight prep: 4 matrices [K=128][N=128] fp32 -> transposed bf16 Wt[n][k] ----
__global__ __launch_bounds__(256) void wconv_k(const float* __restrict__ W1,
    const float* __restrict__ W2, const float* __restrict__ epW1,
    u16* __restrict__ out) {
  int t = blockIdx.x * 256 + threadIdx.x;   // 4 * 16384
  int m = t >> 14, r = t & 16383;
  int n = r >> 7, k = r & 127;
  const float* src = (m == 0) ? W1 : (m == 1) ? W2 : epW1 + (size_t)(m - 2) * 16384;
  out[t] = f2bf(src[k * 128 + n]);
}

// ---- MFMA GEMM: Y_bf16[M,128] = (X[M,128] @ W) (+bias) (* dinv[row]) ----
// Wt[n][k] bf16 transposed weights. 64 rows/block, 4 waves.
template<bool BF16IN, bool SCALE, bool BIAS>
__global__ __launch_bounds__(256) void gemm_mfma_k(const void* __restrict__ Xv,
    const u16* __restrict__ Wt, const float* __restrict__ bias,
    const float* __restrict__ dinv, u16* __restrict__ Y, int M) {
  __shared__ u16 Xs[64][136];   // +8 u16 pad -> 272B row stride, 2-way bank alias (free)
  __shared__ u16 Ws[128][136];
  int tid = threadIdx.x;
  int row0 = blockIdx.x * 64;
  // stage Wt: 128 rows x 16 uint4
  for (int i = tid; i < 2048; i += 256) {
    int n = i >> 4, c8 = i & 15;
    uint4 v = ((const uint4*)Wt)[i];
    *(uint4*)&Ws[n][c8 * 8] = v;
  }
  // stage X: 64 rows x 16 uint4 (8 bf16)
  for (int i = tid; i < 1024; i += 256) {
    int r = i >> 4, c8 = i & 15;
    int gr = row0 + r;
    uint4 v = make_uint4(0u, 0u, 0u, 0u);
    if (gr < M) {
      if (BF16IN) {
        v = ((const uint4*)Xv)[(size_t)gr * 16 + c8];
      } else {
        float4 f0 = ((const float4*)Xv)[(size_t)gr * 32 + c8 * 2];
        float4 f1 = ((const float4*)Xv)[(size_t)gr * 32 + c8 * 2 + 1];
        v.x = packbf2(f0.x, f0.y); v.y = packbf2(f0.z, f0.w);
        v.z = packbf2(f1.x, f1.y); v.w = packbf2(f1.z, f1.w);
      }
    }
    *(uint4*)&Xs[r][c8 * 8] = v;
  }
  __syncthreads();
  int w = tid >> 6, l = tid & 63;
  int lr = l & 15, kq = l >> 4;
  // A frags: row = w*16 + lr, k = kk*32 + kq*8 + j
  bf16x8 a[4];
  #pragma unroll
  for (int kk = 0; kk < 4; ++kk)
    a[kk] = *(const bf16x8*)&Xs[w * 16 + lr][kk * 32 + kq * 8];
  f32x4 acc[8];
  #pragma unroll
  for (int ct = 0; ct < 8; ++ct) {
    f32x4 c = {0.f, 0.f, 0.f, 0.f};
    #pragma unroll
    for (int kk = 0; kk < 4; ++kk) {
      bf16x8 b = *(const bf16x8*)&Ws[ct * 16 + lr][kk * 32 + kq * 8];
      c = __builtin_amdgcn_mfma_f32_16x16x32_bf16(a[kk], b, c, 0, 0, 0);
    }
    acc[ct] = c;
  }
  // epilogue: C/D col = lane&15, row = (lane>>4)*4 + reg
  float sc[4];
  #pragma unroll
  for (int r = 0; r < 4; ++r) {
    int grow = row0 + w * 16 + kq * 4 + r;
    sc[r] = (SCALE && grow < M) ? dinv[grow] : 1.f;
  }
  #pragma unroll
  for (int ct = 0; ct < 8; ++ct) {
    int n = ct * 16 + lr;
    float bv = BIAS ? bias[n] : 0.f;
    #pragma unroll
    for (int r = 0; r < 4; ++r) {
      int grow = row0 + w * 16 + kq * 4 + r;
      if (grow < M) {
        float o = acc[ct][r] + bv;
        if (SCALE) o *= sc[r];
        Y[(size_t)grow * 128 + n] = f2bf(o);
      }
    }
  }
}

// --- per-node gather aggregate + bias + BN(eval) + ReLU (bf16 in/out) ---
__global__ __launch_bounds__(256) void agg_bn_relu_k(const u32* __restrict__ XW,
    const int* __restrict__ rowptr, const int2* __restrict__ se,
    const float* __restrict__ dinv,
    const float* __restrict__ bb, const float* __restrict__ g,
    const float* __restrict__ be, const float* __restrict__ mm,
    const float* __restrict__ vv,
    u32* __restrict__ H, int n) {
  int wid = (blockIdx.x * 256 + threadIdx.x) >> 6;
  if (wid >= n) return;
  int lane = threadIdx.x & 63;
  float ax = 0.f, ay = 0.f;
  int beg = rowptr[wid], end = rowptr[wid + 1];
  int i = beg;
  for (; i + 3 < end; i += 4) {
    int s0 = se[i].x;
    int s1 = se[i + 1].x;
    int s2 = se[i + 2].x;
    int s3 = se[i + 3].x;
    u32 p0 = XW[(size_t)s0 * 64 + lane];
    u32 p1 = XW[(size_t)s1 * 64 + lane];
    u32 p2 = XW[(size_t)s2 * 64 + lane];
    u32 p3 = XW[(size_t)s3 * 64 + lane];
    ax += lo_bf(p0); ay += hi_bf(p0);
    ax += lo_bf(p1); ay += hi_bf(p1);
    ax += lo_bf(p2); ay += hi_bf(p2);
    ax += lo_bf(p3); ay += hi_bf(p3);
  }
  for (; i < end; ++i) {
    u32 p = XW[(size_t)se[i].x * 64 + lane];
    ax += lo_bf(p); ay += hi_bf(p);
  }
  u32 ps = XW[(size_t)wid * 64 + lane];
  ax += lo_bf(ps); ay += hi_bf(ps);
  float dn = dinv[wid];
  ax *= dn; ay *= dn;
  int c = lane * 2;
  float s0 = g[c]     * rsqrtf(vv[c]     + BN_EPS);
  float s1 = g[c + 1] * rsqrtf(vv[c + 1] + BN_EPS);
  float o0 = (ax + bb[c]     - mm[c])     * s0 + be[c];
  float o1 = (ay + bb[c + 1] - mm[c + 1]) * s1 + be[c + 1];
  o0 = fmaxf(o0, 0.f);
  o1 = fmaxf(o1, 0.f);
  H[(size_t)wid * 64 + lane] = packbf2(o0, o1);
}

// ------ edge MLP: sigmoid(relu(A[s]+B[d]) . w2 + b2), thread per edge, CSR order ------
__global__ __launch_bounds__(256) void edge_mlp_k(const u32* __restrict__ A,
    const u32* __restrict__ B, const int2* __restrict__ se,
    const int* __restrict__ csrD,
    const float* __restrict__ w2, const float* __restrict__ b2,
    float* __restrict__ out, int E) {
  int t = blockIdx.x * 256 + threadIdx.x;
  if (t >= E) return;
  int2 p = se[t];
  int s = p.x;
  int e = p.y;
  int d = csrD[t];
  const uint4* Ar = (const uint4*)(A + (size_t)s * 64);
  const uint4* Br = (const uint4*)(B + (size_t)d * 64);
  float acc = 0.f;
  #pragma unroll
  for (int j = 0; j < 16; ++j) {
    uint4 pa = Ar[j];
    uint4 pb = Br[j];
    float4 wa = ((const float4*)w2)[2 * j];
    float4 wb = ((const float4*)w2)[2 * j + 1];
    float h;
    h = fmaxf(lo_bf(pa.x) + lo_bf(pb.x), 0.f); acc = fmaf(h, wa.x, acc);
    h = fmaxf(hi_bf(pa.x) + hi_bf(pb.x), 0.f); acc = fmaf(h, wa.y, acc);
    h = fmaxf(lo_bf(pa.y) + lo_bf(pb.y), 0.f); acc = fmaf(h, wa.z, acc);
    h = fmaxf(hi_bf(pa.y) + hi_bf(pb.y), 0.f); acc = fmaf(h, wa.w, acc);
    h = fmaxf(lo_bf(pa.z) + lo_bf(pb.z), 0.f); acc = fmaf(h, wb.x, acc);
    h = fmaxf(hi_bf(pa.z) + hi_bf(pb.z), 0.f); acc = fmaf(h, wb.y, acc);
    h = fmaxf(lo_bf(pa.w) + lo_bf(pb.w), 0.f); acc = fmaf(h, wb.z, acc);
    h = fmaxf(hi_bf(pa.w) + hi_bf(pb.w), 0.f); acc = fmaf(h, wb.w, acc);
  }
  float z = acc + b2[0];
  out[e] = 1.f / (1.f + expf(-z));
}

extern "C" void kernel_launch(void* const* d_in, const int* in_sizes, int n_in,
                              void* d_out, int out_size, void* d_ws, size_t ws_size,
                              hipStream_t stream) {
  const float* x    = (const float*)d_in[0];
  const int*   ei   = (const int*)d_in[1];
  const float* W1   = (const float*)d_in[2];
  const float* b1   = (const float*)d_in[3];
  const float* g1   = (const float*)d_in[4];
  const float* be1  = (const float*)d_in[5];
  const float* m1   = (const float*)d_in[6];
  const float* v1   = (const float*)d_in[7];
  const float* W2   = (const float*)d_in[8];
  const float* b2   = (const float*)d_in[9];
  const float* g2   = (const float*)d_in[10];
  const float* be2  = (const float*)d_in[11];
  const float* m2   = (const float*)d_in[12];
  const float* v2   = (const float*)d_in[13];
  const float* epW1 = (const float*)d_in[14];
  const float* epb1 = (const float*)d_in[15];
  const float* epW2 = (const float*)d_in[16];
  const float* epb2 = (const float*)d_in[17];

  int N = in_sizes[0] / 128;
  int E = in_sizes[1] / 2;
  const int* src = ei;
  const int* dst = ei + E;

  char* w = (char*)d_ws;
  size_t off = 0;
  auto carve = [&](size_t bytes) {
    void* p = w + off;
    off = (off + bytes + 255) & ~(size_t)255;
    return p;
  };
  u16* bufX  = (u16*)carve((size_t)N * 128 * 2);  // xw' -> t2' -> A
  u16* bufH  = (u16*)carve((size_t)N * 128 * 2);  // h1 -> h2
  u16* bufB  = (u16*)carve((size_t)N * 128 * 2);  // B
  int*   cnt   = (int*)carve((size_t)N * 4);
  int*   fill  = (int*)carve((size_t)N * 4);
  int*   rowptr= (int*)carve((size_t)(N + 1) * 4);
  float* dinv  = (float*)carve((size_t)N * 4);
  int2*  se    = (int2*)carve((size_t)E * 8);
  int*   csrD  = (int*)carve((size_t)E * 4);
  int*   bsum  = (int*)carve((size_t)1024 * 4);
  u16*   wsT   = (u16*)carve((size_t)4 * 16384 * 2);  // 4 transposed bf16 weights
  (void)ws_size; (void)n_in; (void)out_size;

  int nb = (N + 255) / 256;

  hipMemsetAsync(cnt, 0, (size_t)N * 4, stream);
  hipMemsetAsync(fill, 0, (size_t)N * 4, stream);
  wconv_k<<<256, 256, 0, stream>>>(W1, W2, epW1, wsT);
  count_dst_k<<<(E + 255) / 256, 256, 0, stream>>>(dst, cnt, E);
  blocksum_k<<<nb, 256, 0, stream>>>(cnt, bsum, N);
  scan_bsum_k<<<1, 1024, 0, stream>>>(bsum, nb);
  scan_final_k<<<nb, 256, 0, stream>>>(cnt, bsum, rowptr, dinv, N);
  fill_csr_k<<<(E + 255) / 256, 256, 0, stream>>>(src, dst, rowptr, fill, se, E);
  expand_dst_k<<<nb, 256, 0, stream>>>(rowptr, csrD, N);

  int gb = (N + 63) / 64;
  int ab = (N + 3) / 4;
  const u16* WtW1 = wsT;
  const u16* WtW2 = wsT + 16384;
  const u16* WtA  = wsT + 2 * 16384;
  const u16* WtB  = wsT + 3 * 16384;

  // layer 1: XW' = dinv * (x @ W1)
  gemm_mfma_k<false, true, false><<<gb, 256, 0, stream>>>(x, WtW1, nullptr, dinv, bufX, N);
  agg_bn_relu_k<<<ab, 256, 0, stream>>>((const u32*)bufX, rowptr, se, dinv,
                                        b1, g1, be1, m1, v1, (u32*)bufH, N);
  // layer 2
  gemm_mfma_k<true, true, false><<<gb, 256, 0, stream>>>(bufH, WtW2, nullptr, dinv, bufX, N);
  agg_bn_relu_k<<<ab, 256, 0, stream>>>((const u32*)bufX, rowptr, se, dinv,
                                        b2, g2, be2, m2, v2, (u32*)bufH, N);
  // edge predictor: A = h2 @ epW1[:128] + epb1 ; B = h2 @ epW1[128:]
  gemm_mfma_k<true, false, true><<<gb, 256, 0, stream>>>(bufH, WtA, epb1, nullptr, bufX, N);
  gemm_mfma_k<true, false, false><<<gb, 256, 0, stream>>>(bufH, WtB, nullptr, nullptr, bufB, N);
  // per-edge MLP + sigmoid (CSR order: B-row gathers L1-resident)
  edge_mlp_k<<<(E + 255) / 256, 256, 0, stream>>>((const u32*)bufX, (const u32*)bufB,
                                                  se, csrD, epW2, epb2,
                                                  (float*)d_out, E);
}

// Round 6
// 280.138 us; speedup vs baseline: 2.4007x; 1.1513x over previous
//
#include <hip/hip_runtime.h>
#include <math.h>

#define BN_EPS 1e-5f

typedef unsigned short u16;
typedef unsigned int u32;
typedef __attribute__((ext_vector_type(8))) short bf16x8;
typedef __attribute__((ext_vector_type(4))) float f32x4;

__device__ __forceinline__ float bf2f(u16 b) {
  return __uint_as_float(((u32)b) << 16);
}
__device__ __forceinline__ u16 f2bf(float f) {
  u32 u = __float_as_uint(f);
  u32 r = (u + 0x7fffu + ((u >> 16) & 1u)) >> 16;   // RNE
  return (u16)r;
}
__device__ __forceinline__ float2 bfx2(u32 p) {
  return make_float2(bf2f((u16)(p & 0xffffu)), bf2f((u16)(p >> 16)));
}
__device__ __forceinline__ u32 packbf2(float x, float y) {
  return (u32)f2bf(x) | ((u32)f2bf(y) << 16);
}
__device__ __forceinline__ float lo_bf(u32 p) { return __uint_as_float(p << 16); }
__device__ __forceinline__ float hi_bf(u32 p) { return __uint_as_float(p & 0xffff0000u); }

// ---------------- CSR build ----------------
// count + record intra-row position (atomic return), x4 ILP
__global__ __launch_bounds__(256) void count_pos_k(const int* __restrict__ dst,
                                                   int* __restrict__ cnt,
                                                   int* __restrict__ pintra,
                                                   int T, int E) {
  int t = blockIdx.x * 256 + threadIdx.x;
  if (t >= T) return;
  int e0 = t, e1 = t + T, e2 = t + 2 * T, e3 = t + 3 * T;
  int d0 = (e0 < E) ? dst[e0] : -1;
  int d1 = (e1 < E) ? dst[e1] : -1;
  int d2 = (e2 < E) ? dst[e2] : -1;
  int d3 = (e3 < E) ? dst[e3] : -1;
  int p0 = (d0 >= 0) ? atomicAdd(&cnt[d0], 1) : 0;
  int p1 = (d1 >= 0) ? atomicAdd(&cnt[d1], 1) : 0;
  int p2 = (d2 >= 0) ? atomicAdd(&cnt[d2], 1) : 0;
  int p3 = (d3 >= 0) ? atomicAdd(&cnt[d3], 1) : 0;
  if (d0 >= 0) pintra[e0] = p0;
  if (d1 >= 0) pintra[e1] = p1;
  if (d2 >= 0) pintra[e2] = p2;
  if (d3 >= 0) pintra[e3] = p3;
}

__global__ __launch_bounds__(256) void blocksum_k(const int* __restrict__ cnt,
                                                  int* __restrict__ bsum, int n) {
  __shared__ int red[256];
  int tid = threadIdx.x;
  int i = blockIdx.x * 256 + tid;
  int v = (i < n) ? cnt[i] : 0;
  red[tid] = v;
  __syncthreads();
  for (int o = 128; o > 0; o >>= 1) {
    if (tid < o) red[tid] += red[tid + o];
    __syncthreads();
  }
  if (tid == 0) bsum[blockIdx.x] = red[0];
}

__global__ __launch_bounds__(1024) void scan_bsum_k(int* __restrict__ bsum, int nb) {
  __shared__ int part[1024];
  int tid = threadIdx.x;
  int v = (tid < nb) ? bsum[tid] : 0;
  part[tid] = v;
  __syncthreads();
  for (int o = 1; o < 1024; o <<= 1) {
    int t = (tid >= o) ? part[tid - o] : 0;
    __syncthreads();
    part[tid] += t;
    __syncthreads();
  }
  if (tid < nb) bsum[tid] = part[tid] - v;   // exclusive
}

__global__ __launch_bounds__(256) void scan_final_k(const int* __restrict__ cnt,
                                                    const int* __restrict__ bsum,
                                                    int* __restrict__ rowptr,
                                                    float* __restrict__ dinv, int n) {
  __shared__ int part[256];
  int tid = threadIdx.x;
  int i = blockIdx.x * 256 + tid;
  int v = (i < n) ? cnt[i] : 0;
  part[tid] = v;
  __syncthreads();
  for (int o = 1; o < 256; o <<= 1) {
    int t = (tid >= o) ? part[tid - o] : 0;
    __syncthreads();
    part[tid] += t;
    __syncthreads();
  }
  if (i < n) {
    int excl = part[tid] - v + bsum[blockIdx.x];
    rowptr[i] = excl;
    dinv[i] = rsqrtf((float)(v + 1));   // deg = in-degree + self-loop
    if (i == n - 1) rowptr[n] = excl + v;
  }
}

// scattered 8B store per edge, NO atomic (position precomputed), x4 ILP
__global__ __launch_bounds__(256) void fill_csr_k(const int* __restrict__ src,
                                                  const int* __restrict__ dst,
                                                  const int* __restrict__ rowptr,
                                                  const int* __restrict__ pintra,
                                                  int2* __restrict__ se, int T, int E) {
  int t = blockIdx.x * 256 + threadIdx.x;
  if (t >= T) return;
  #pragma unroll
  for (int u = 0; u < 4; ++u) {
    int e = t + u * T;
    if (e < E) {
      int d = dst[e];
      int p = rowptr[d] + pintra[e];
      se[p] = make_int2(src[e], e);
    }
  }
}

__global__ void expand_dst_k(const int* __restrict__ rowptr, int* __restrict__ csrD, int n) {
  int i = blockIdx.x * blockDim.x + threadIdx.x;
  if (i < n) {
    int b = rowptr[i], e = rowptr[i + 1];
    for (int j = b; j < e; ++j) csrD[j] = i;
  }
}

// ---- weight prep: 4 matrices [K=128][N=128] fp32 -> transposed bf16 Wt[n][k] ----
__global__ __launch_bounds__(256) void wconv_k(const float* __restrict__ W1,
    const float* __restrict__ W2, const float* __restrict__ epW1,
    u16* __restrict__ out) {
  int t = blockIdx.x * 256 + threadIdx.x;   // 4 * 16384
  int m = t >> 14, r = t & 16383;
  int n = r >> 7, k = r & 127;
  const float* src = (m == 0) ? W1 : (m == 1) ? W2 : epW1 + (size_t)(m - 2) * 16384;
  out[t] = f2bf(src[k * 128 + n]);
}

// ---- MFMA GEMM: Y_bf16[M,128] = (X[M,128] @ W) (+bias) (* dinv[row]) ----
// Wt[n][k] bf16 transposed weights. 64 rows/block, 4 waves.
template<bool BF16IN, bool SCALE, bool BIAS>
__global__ __launch_bounds__(256) void gemm_mfma_k(const void* __restrict__ Xv,
    const u16* __restrict__ Wt, const float* __restrict__ bias,
    const float* __restrict__ dinv, u16* __restrict__ Y, int M) {
  __shared__ u16 Xs[64][136];   // +8 u16 pad -> 272B row stride, 2-way bank alias (free)
  __shared__ u16 Ws[128][136];
  int tid = threadIdx.x;
  int row0 = blockIdx.x * 64;
  // stage Wt: 128 rows x 16 uint4
  for (int i = tid; i < 2048; i += 256) {
    int n = i >> 4, c8 = i & 15;
    uint4 v = ((const uint4*)Wt)[i];
    *(uint4*)&Ws[n][c8 * 8] = v;
  }
  // stage X: 64 rows x 16 uint4 (8 bf16)
  for (int i = tid; i < 1024; i += 256) {
    int r = i >> 4, c8 = i & 15;
    int gr = row0 + r;
    uint4 v = make_uint4(0u, 0u, 0u, 0u);
    if (gr < M) {
      if (BF16IN) {
        v = ((const uint4*)Xv)[(size_t)gr * 16 + c8];
      } else {
        float4 f0 = ((const float4*)Xv)[(size_t)gr * 32 + c8 * 2];
        float4 f1 = ((const float4*)Xv)[(size_t)gr * 32 + c8 * 2 + 1];
        v.x = packbf2(f0.x, f0.y); v.y = packbf2(f0.z, f0.w);
        v.z = packbf2(f1.x, f1.y); v.w = packbf2(f1.z, f1.w);
      }
    }
    *(uint4*)&Xs[r][c8 * 8] = v;
  }
  __syncthreads();
  int w = tid >> 6, l = tid & 63;
  int lr = l & 15, kq = l >> 4;
  // A frags: row = w*16 + lr, k = kk*32 + kq*8 + j
  bf16x8 a[4];
  #pragma unroll
  for (int kk = 0; kk < 4; ++kk)
    a[kk] = *(const bf16x8*)&Xs[w * 16 + lr][kk * 32 + kq * 8];
  f32x4 acc[8];
  #pragma unroll
  for (int ct = 0; ct < 8; ++ct) {
    f32x4 c = {0.f, 0.f, 0.f, 0.f};
    #pragma unroll
    for (int kk = 0; kk < 4; ++kk) {
      bf16x8 b = *(const bf16x8*)&Ws[ct * 16 + lr][kk * 32 + kq * 8];
      c = __builtin_amdgcn_mfma_f32_16x16x32_bf16(a[kk], b, c, 0, 0, 0);
    }
    acc[ct] = c;
  }
  // epilogue: C/D col = lane&15, row = (lane>>4)*4 + reg
  float sc[4];
  #pragma unroll
  for (int r = 0; r < 4; ++r) {
    int grow = row0 + w * 16 + kq * 4 + r;
    sc[r] = (SCALE && grow < M) ? dinv[grow] : 1.f;
  }
  #pragma unroll
  for (int ct = 0; ct < 8; ++ct) {
    int n = ct * 16 + lr;
    float bv = BIAS ? bias[n] : 0.f;
    #pragma unroll
    for (int r = 0; r < 4; ++r) {
      int grow = row0 + w * 16 + kq * 4 + r;
      if (grow < M) {
        float o = acc[ct][r] + bv;
        if (SCALE) o *= sc[r];
        Y[(size_t)grow * 128 + n] = f2bf(o);
      }
    }
  }
}

// --- per-node gather aggregate + bias + BN(eval) + ReLU (bf16 in/out) ---
__global__ __launch_bounds__(256) void agg_bn_relu_k(const u32* __restrict__ XW,
    const int* __restrict__ rowptr, const int2* __restrict__ se,
    const float* __restrict__ dinv,
    const float* __restrict__ bb, const float* __restrict__ g,
    const float* __restrict__ be, const float* __restrict__ mm,
    const float* __restrict__ vv,
    u32* __restrict__ H, int n) {
  int wid = (blockIdx.x * 256 + threadIdx.x) >> 6;
  if (wid >= n) return;
  int lane = threadIdx.x & 63;
  float ax = 0.f, ay = 0.f;
  int beg = rowptr[wid], end = rowptr[wid + 1];
  int i = beg;
  for (; i + 3 < end; i += 4) {
    int s0 = se[i].x;
    int s1 = se[i + 1].x;
    int s2 = se[i + 2].x;
    int s3 = se[i + 3].x;
    u32 p0 = XW[(size_t)s0 * 64 + lane];
    u32 p1 = XW[(size_t)s1 * 64 + lane];
    u32 p2 = XW[(size_t)s2 * 64 + lane];
    u32 p3 = XW[(size_t)s3 * 64 + lane];
    ax += lo_bf(p0); ay += hi_bf(p0);
    ax += lo_bf(p1); ay += hi_bf(p1);
    ax += lo_bf(p2); ay += hi_bf(p2);
    ax += lo_bf(p3); ay += hi_bf(p3);
  }
  for (; i < end; ++i) {
    u32 p = XW[(size_t)se[i].x * 64 + lane];
    ax += lo_bf(p); ay += hi_bf(p);
  }
  u32 ps = XW[(size_t)wid * 64 + lane];
  ax += lo_bf(ps); ay += hi_bf(ps);
  float dn = dinv[wid];
  ax *= dn; ay *= dn;
  int c = lane * 2;
  float s0 = g[c]     * rsqrtf(vv[c]     + BN_EPS);
  float s1 = g[c + 1] * rsqrtf(vv[c + 1] + BN_EPS);
  float o0 = (ax + bb[c]     - mm[c])     * s0 + be[c];
  float o1 = (ay + bb[c + 1] - mm[c + 1]) * s1 + be[c + 1];
  o0 = fmaxf(o0, 0.f);
  o1 = fmaxf(o1, 0.f);
  H[(size_t)wid * 64 + lane] = packbf2(o0, o1);
}

// ------ edge MLP: sigmoid(relu(A[s]+B[d]) . w2 + b2), thread per edge, CSR order ------
__global__ __launch_bounds__(256) void edge_mlp_k(const u32* __restrict__ A,
    const u32* __restrict__ B, const int2* __restrict__ se,
    const int* __restrict__ csrD,
    const float* __restrict__ w2, const float* __restrict__ b2,
    float* __restrict__ out, int E) {
  int t = blockIdx.x * 256 + threadIdx.x;
  if (t >= E) return;
  int2 p = se[t];
  int s = p.x;
  int e = p.y;
  int d = csrD[t];
  const uint4* Ar = (const uint4*)(A + (size_t)s * 64);
  const uint4* Br = (const uint4*)(B + (size_t)d * 64);
  float acc = 0.f;
  #pragma unroll
  for (int j = 0; j < 16; ++j) {
    uint4 pa = Ar[j];
    uint4 pb = Br[j];
    float4 wa = ((const float4*)w2)[2 * j];
    float4 wb = ((const float4*)w2)[2 * j + 1];
    float h;
    h = fmaxf(lo_bf(pa.x) + lo_bf(pb.x), 0.f); acc = fmaf(h, wa.x, acc);
    h = fmaxf(hi_bf(pa.x) + hi_bf(pb.x), 0.f); acc = fmaf(h, wa.y, acc);
    h = fmaxf(lo_bf(pa.y) + lo_bf(pb.y), 0.f); acc = fmaf(h, wa.z, acc);
    h = fmaxf(hi_bf(pa.y) + hi_bf(pb.y), 0.f); acc = fmaf(h, wa.w, acc);
    h = fmaxf(lo_bf(pa.z) + lo_bf(pb.z), 0.f); acc = fmaf(h, wb.x, acc);
    h = fmaxf(hi_bf(pa.z) + hi_bf(pb.z), 0.f); acc = fmaf(h, wb.y, acc);
    h = fmaxf(lo_bf(pa.w) + lo_bf(pb.w), 0.f); acc = fmaf(h, wb.z, acc);
    h = fmaxf(hi_bf(pa.w) + hi_bf(pb.w), 0.f); acc = fmaf(h, wb.w, acc);
  }
  float z = acc + b2[0];
  out[e] = 1.f / (1.f + expf(-z));
}

extern "C" void kernel_launch(void* const* d_in, const int* in_sizes, int n_in,
                              void* d_out, int out_size, void* d_ws, size_t ws_size,
                              hipStream_t stream) {
  const float* x    = (const float*)d_in[0];
  const int*   ei   = (const int*)d_in[1];
  const float* W1   = (const float*)d_in[2];
  const float* b1   = (const float*)d_in[3];
  const float* g1   = (const float*)d_in[4];
  const float* be1  = (const float*)d_in[5];
  const float* m1   = (const float*)d_in[6];
  const float* v1   = (const float*)d_in[7];
  const float* W2   = (const float*)d_in[8];
  const float* b2   = (const float*)d_in[9];
  const float* g2   = (const float*)d_in[10];
  const float* be2  = (const float*)d_in[11];
  const float* m2   = (const float*)d_in[12];
  const float* v2   = (const float*)d_in[13];
  const float* epW1 = (const float*)d_in[14];
  const float* epb1 = (const float*)d_in[15];
  const float* epW2 = (const float*)d_in[16];
  const float* epb2 = (const float*)d_in[17];

  int N = in_sizes[0] / 128;
  int E = in_sizes[1] / 2;
  const int* src = ei;
  const int* dst = ei + E;

  char* w = (char*)d_ws;
  size_t off = 0;
  auto carve = [&](size_t bytes) {
    void* p = w + off;
    off = (off + bytes + 255) & ~(size_t)255;
    return p;
  };
  u16* bufX  = (u16*)carve((size_t)N * 128 * 2);  // xw' -> t2' -> A
  u16* bufH  = (u16*)carve((size_t)N * 128 * 2);  // h1 -> h2
  u16* bufB  = (u16*)carve((size_t)N * 128 * 2);  // B
  int*   cnt   = (int*)carve((size_t)N * 4);
  int*   pintra= (int*)carve((size_t)E * 4);
  int*   rowptr= (int*)carve((size_t)(N + 1) * 4);
  float* dinv  = (float*)carve((size_t)N * 4);
  int2*  se    = (int2*)carve((size_t)E * 8);
  int*   csrD  = (int*)carve((size_t)E * 4);
  int*   bsum  = (int*)carve((size_t)1024 * 4);
  u16*   wsT   = (u16*)carve((size_t)4 * 16384 * 2);  // 4 transposed bf16 weights
  (void)ws_size; (void)n_in; (void)out_size;

  int nb = (N + 255) / 256;
  int T = (E + 3) / 4;
  int tb = (T + 255) / 256;

  hipMemsetAsync(cnt, 0, (size_t)N * 4, stream);
  wconv_k<<<256, 256, 0, stream>>>(W1, W2, epW1, wsT);
  count_pos_k<<<tb, 256, 0, stream>>>(dst, cnt, pintra, T, E);
  blocksum_k<<<nb, 256, 0, stream>>>(cnt, bsum, N);
  scan_bsum_k<<<1, 1024, 0, stream>>>(bsum, nb);
  scan_final_k<<<nb, 256, 0, stream>>>(cnt, bsum, rowptr, dinv, N);
  fill_csr_k<<<tb, 256, 0, stream>>>(src, dst, rowptr, pintra, se, T, E);
  expand_dst_k<<<nb, 256, 0, stream>>>(rowptr, csrD, N);

  int gb = (N + 63) / 64;
  int ab = (N + 3) / 4;
  const u16* WtW1 = wsT;
  const u16* WtW2 = wsT + 16384;
  const u16* WtA  = wsT + 2 * 16384;
  const u16* WtB  = wsT + 3 * 16384;

  // layer 1: XW' = dinv * (x @ W1)
  gemm_mfma_k<false, true, false><<<gb, 256, 0, stream>>>(x, WtW1, nullptr, dinv, bufX, N);
  agg_bn_relu_k<<<ab, 256, 0, stream>>>((const u32*)bufX, rowptr, se, dinv,
                                        b1, g1, be1, m1, v1, (u32*)bufH, N);
  // layer 2
  gemm_mfma_k<true, true, false><<<gb, 256, 0, stream>>>(bufH, WtW2, nullptr, dinv, bufX, N);
  agg_bn_relu_k<<<ab, 256, 0, stream>>>((const u32*)bufX, rowptr, se, dinv,
                                        b2, g2, be2, m2, v2, (u32*)bufH, N);
  // edge predictor: A = h2 @ epW1[:128] + epb1 ; B = h2 @ epW1[128:]
  gemm_mfma_k<true, false, true><<<gb, 256, 0, stream>>>(bufH, WtA, epb1, nullptr, bufX, N);
  gemm_mfma_k<true, false, false><<<gb, 256, 0, stream>>>(bufH, WtB, nullptr, nullptr, bufB, N);
  // per-edge MLP + sigmoid (CSR order: B-row gathers L1-resident)
  edge_mlp_k<<<(E + 255) / 256, 256, 0, stream>>>((const u32*)bufX, (const u32*)bufB,
                                                  se, csrD, epW2, epb2,
                                                  (float*)d_out, E);
}

// Round 7
// 274.348 us; speedup vs baseline: 2.4513x; 1.0211x over previous
//
#include <hip/hip_runtime.h>
#include <math.h>

#define BN_EPS 1e-5f

typedef unsigned short u16;
typedef unsigned int u32;
typedef __attribute__((ext_vector_type(8))) short bf16x8;
typedef __attribute__((ext_vector_type(4))) float f32x4;

__device__ __forceinline__ float bf2f(u16 b) {
  return __uint_as_float(((u32)b) << 16);
}
__device__ __forceinline__ u16 f2bf(float f) {
  u32 u = __float_as_uint(f);
  u32 r = (u + 0x7fffu + ((u >> 16) & 1u)) >> 16;   // RNE
  return (u16)r;
}
__device__ __forceinline__ float2 bfx2(u32 p) {
  return make_float2(bf2f((u16)(p & 0xffffu)), bf2f((u16)(p >> 16)));
}
__device__ __forceinline__ u32 packbf2(float x, float y) {
  return (u32)f2bf(x) | ((u32)f2bf(y) << 16);
}
__device__ __forceinline__ float lo_bf(u32 p) { return __uint_as_float(p << 16); }
__device__ __forceinline__ float hi_bf(u32 p) { return __uint_as_float(p & 0xffff0000u); }

__device__ __forceinline__ void unpack8(uint4 p, float* f) {
  f[0] = lo_bf(p.x); f[1] = hi_bf(p.x);
  f[2] = lo_bf(p.y); f[3] = hi_bf(p.y);
  f[4] = lo_bf(p.z); f[5] = hi_bf(p.z);
  f[6] = lo_bf(p.w); f[7] = hi_bf(p.w);
}

// ---------------- CSR build ----------------
// count + record intra-row position (atomic return), x4 ILP
__global__ __launch_bounds__(256) void count_pos_k(const int* __restrict__ dst,
                                                   int* __restrict__ cnt,
                                                   int* __restrict__ pintra,
                                                   int T, int E) {
  int t = blockIdx.x * 256 + threadIdx.x;
  if (t >= T) return;
  int e0 = t, e1 = t + T, e2 = t + 2 * T, e3 = t + 3 * T;
  int d0 = (e0 < E) ? dst[e0] : -1;
  int d1 = (e1 < E) ? dst[e1] : -1;
  int d2 = (e2 < E) ? dst[e2] : -1;
  int d3 = (e3 < E) ? dst[e3] : -1;
  int p0 = (d0 >= 0) ? atomicAdd(&cnt[d0], 1) : 0;
  int p1 = (d1 >= 0) ? atomicAdd(&cnt[d1], 1) : 0;
  int p2 = (d2 >= 0) ? atomicAdd(&cnt[d2], 1) : 0;
  int p3 = (d3 >= 0) ? atomicAdd(&cnt[d3], 1) : 0;
  if (d0 >= 0) pintra[e0] = p0;
  if (d1 >= 0) pintra[e1] = p1;
  if (d2 >= 0) pintra[e2] = p2;
  if (d3 >= 0) pintra[e3] = p3;
}

__global__ __launch_bounds__(256) void blocksum_k(const int* __restrict__ cnt,
                                                  int* __restrict__ bsum, int n) {
  __shared__ int red[256];
  int tid = threadIdx.x;
  int i = blockIdx.x * 256 + tid;
  int v = (i < n) ? cnt[i] : 0;
  red[tid] = v;
  __syncthreads();
  for (int o = 128; o > 0; o >>= 1) {
    if (tid < o) red[tid] += red[tid + o];
    __syncthreads();
  }
  if (tid == 0) bsum[blockIdx.x] = red[0];
}

__global__ __launch_bounds__(1024) void scan_bsum_k(int* __restrict__ bsum, int nb) {
  __shared__ int part[1024];
  int tid = threadIdx.x;
  int v = (tid < nb) ? bsum[tid] : 0;
  part[tid] = v;
  __syncthreads();
  for (int o = 1; o < 1024; o <<= 1) {
    int t = (tid >= o) ? part[tid - o] : 0;
    __syncthreads();
    part[tid] += t;
    __syncthreads();
  }
  if (tid < nb) bsum[tid] = part[tid] - v;   // exclusive
}

__global__ __launch_bounds__(256) void scan_final_k(const int* __restrict__ cnt,
                                                    const int* __restrict__ bsum,
                                                    int* __restrict__ rowptr,
                                                    float* __restrict__ dinv, int n) {
  __shared__ int part[256];
  int tid = threadIdx.x;
  int i = blockIdx.x * 256 + tid;
  int v = (i < n) ? cnt[i] : 0;
  part[tid] = v;
  __syncthreads();
  for (int o = 1; o < 256; o <<= 1) {
    int t = (tid >= o) ? part[tid - o] : 0;
    __syncthreads();
    part[tid] += t;
    __syncthreads();
  }
  if (i < n) {
    int excl = part[tid] - v + bsum[blockIdx.x];
    rowptr[i] = excl;
    dinv[i] = rsqrtf((float)(v + 1));   // deg = in-degree + self-loop
    if (i == n - 1) rowptr[n] = excl + v;
  }
}

// scattered 8B store per edge, NO atomic (position precomputed), x4 ILP
__global__ __launch_bounds__(256) void fill_csr_k(const int* __restrict__ src,
                                                  const int* __restrict__ dst,
                                                  const int* __restrict__ rowptr,
                                                  const int* __restrict__ pintra,
                                                  int2* __restrict__ se, int T, int E) {
  int t = blockIdx.x * 256 + threadIdx.x;
  if (t >= T) return;
  #pragma unroll
  for (int u = 0; u < 4; ++u) {
    int e = t + u * T;
    if (e < E) {
      int d = dst[e];
      int p = rowptr[d] + pintra[e];
      se[p] = make_int2(src[e], e);
    }
  }
}

// ---- weight prep: 4 matrices [K=128][N=128] fp32 -> transposed bf16 Wt[n][k] ----
__global__ __launch_bounds__(256) void wconv_k(const float* __restrict__ W1,
    const float* __restrict__ W2, const float* __restrict__ epW1,
    u16* __restrict__ out) {
  int t = blockIdx.x * 256 + threadIdx.x;   // 4 * 16384
  int m = t >> 14, r = t & 16383;
  int n = r >> 7, k = r & 127;
  const float* src = (m == 0) ? W1 : (m == 1) ? W2 : epW1 + (size_t)(m - 2) * 16384;
  out[t] = f2bf(src[k * 128 + n]);
}

// ---- MFMA GEMM: Y_bf16[M,128] = (X[M,128] @ W) (+bias) (* dinv[row]) ----
// Wt[n][k] bf16 transposed weights. 64 rows/block, 4 waves.
template<bool BF16IN, bool SCALE, bool BIAS>
__global__ __launch_bounds__(256) void gemm_mfma_k(const void* __restrict__ Xv,
    const u16* __restrict__ Wt, const float* __restrict__ bias,
    const float* __restrict__ dinv, u16* __restrict__ Y, int M) {
  __shared__ u16 Xs[64][136];   // +8 u16 pad -> 272B row stride, 2-way bank alias (free)
  __shared__ u16 Ws[128][136];
  int tid = threadIdx.x;
  int row0 = blockIdx.x * 64;
  // stage Wt: 128 rows x 16 uint4
  for (int i = tid; i < 2048; i += 256) {
    int n = i >> 4, c8 = i & 15;
    uint4 v = ((const uint4*)Wt)[i];
    *(uint4*)&Ws[n][c8 * 8] = v;
  }
  // stage X: 64 rows x 16 uint4 (8 bf16)
  for (int i = tid; i < 1024; i += 256) {
    int r = i >> 4, c8 = i & 15;
    int gr = row0 + r;
    uint4 v = make_uint4(0u, 0u, 0u, 0u);
    if (gr < M) {
      if (BF16IN) {
        v = ((const uint4*)Xv)[(size_t)gr * 16 + c8];
      } else {
        float4 f0 = ((const float4*)Xv)[(size_t)gr * 32 + c8 * 2];
        float4 f1 = ((const float4*)Xv)[(size_t)gr * 32 + c8 * 2 + 1];
        v.x = packbf2(f0.x, f0.y); v.y = packbf2(f0.z, f0.w);
        v.z = packbf2(f1.x, f1.y); v.w = packbf2(f1.z, f1.w);
      }
    }
    *(uint4*)&Xs[r][c8 * 8] = v;
  }
  __syncthreads();
  int w = tid >> 6, l = tid & 63;
  int lr = l & 15, kq = l >> 4;
  bf16x8 a[4];
  #pragma unroll
  for (int kk = 0; kk < 4; ++kk)
    a[kk] = *(const bf16x8*)&Xs[w * 16 + lr][kk * 32 + kq * 8];
  f32x4 acc[8];
  #pragma unroll
  for (int ct = 0; ct < 8; ++ct) {
    f32x4 c = {0.f, 0.f, 0.f, 0.f};
    #pragma unroll
    for (int kk = 0; kk < 4; ++kk) {
      bf16x8 b = *(const bf16x8*)&Ws[ct * 16 + lr][kk * 32 + kq * 8];
      c = __builtin_amdgcn_mfma_f32_16x16x32_bf16(a[kk], b, c, 0, 0, 0);
    }
    acc[ct] = c;
  }
  float sc[4];
  #pragma unroll
  for (int r = 0; r < 4; ++r) {
    int grow = row0 + w * 16 + kq * 4 + r;
    sc[r] = (SCALE && grow < M) ? dinv[grow] : 1.f;
  }
  #pragma unroll
  for (int ct = 0; ct < 8; ++ct) {
    int n = ct * 16 + lr;
    float bv = BIAS ? bias[n] : 0.f;
    #pragma unroll
    for (int r = 0; r < 4; ++r) {
      int grow = row0 + w * 16 + kq * 4 + r;
      if (grow < M) {
        float o = acc[ct][r] + bv;
        if (SCALE) o *= sc[r];
        Y[(size_t)grow * 128 + n] = f2bf(o);
      }
    }
  }
}

// ---- fused double GEMM: YA = X@WA + bias, YB = X@WB (shared X staging) ----
__global__ __launch_bounds__(256) void gemm_mfma2_k(const u16* __restrict__ X,
    const u16* __restrict__ WtA, const u16* __restrict__ WtB,
    const float* __restrict__ bias, u16* __restrict__ YA, u16* __restrict__ YB, int M) {
  __shared__ u16 Xs[64][136];
  __shared__ u16 Ws[128][136];
  int tid = threadIdx.x;
  int row0 = blockIdx.x * 64;
  for (int i = tid; i < 1024; i += 256) {
    int r = i >> 4, c8 = i & 15;
    int gr = row0 + r;
    uint4 v = make_uint4(0u, 0u, 0u, 0u);
    if (gr < M) v = ((const uint4*)X)[(size_t)gr * 16 + c8];
    *(uint4*)&Xs[r][c8 * 8] = v;
  }
  __syncthreads();
  int w = tid >> 6, l = tid & 63;
  int lr = l & 15, kq = l >> 4;
  bf16x8 a[4];
  #pragma unroll
  for (int kk = 0; kk < 4; ++kk)
    a[kk] = *(const bf16x8*)&Xs[w * 16 + lr][kk * 32 + kq * 8];

  for (int m = 0; m < 2; ++m) {
    const u16* Wt = m ? WtB : WtA;
    u16* Y = m ? YB : YA;
    __syncthreads();   // m=0: after X stage (no-op extra); m=1: prior Ws reads done
    for (int i = tid; i < 2048; i += 256) {
      int n = i >> 4, c8 = i & 15;
      uint4 v = ((const uint4*)Wt)[i];
      *(uint4*)&Ws[n][c8 * 8] = v;
    }
    __syncthreads();
    #pragma unroll
    for (int ct = 0; ct < 8; ++ct) {
      f32x4 c = {0.f, 0.f, 0.f, 0.f};
      #pragma unroll
      for (int kk = 0; kk < 4; ++kk) {
        bf16x8 b = *(const bf16x8*)&Ws[ct * 16 + lr][kk * 32 + kq * 8];
        c = __builtin_amdgcn_mfma_f32_16x16x32_bf16(a[kk], b, c, 0, 0, 0);
      }
      int n = ct * 16 + lr;
      float bv = (m == 0) ? bias[n] : 0.f;
      #pragma unroll
      for (int r = 0; r < 4; ++r) {
        int grow = row0 + w * 16 + kq * 4 + r;
        if (grow < M) Y[(size_t)grow * 128 + n] = f2bf(c[r] + bv);
      }
    }
  }
}

// --- agg: wave per node, 4 edges/iteration (lane = 16*sub + l16, uint4 gathers) ---
// XW rows pre-scaled by dinv[row]; out[d] = BN(relu-less...) per reference chain
__global__ __launch_bounds__(256) void agg_bn_relu_k(const uint4* __restrict__ XW4,
    const int* __restrict__ rowptr, const int2* __restrict__ se,
    const float* __restrict__ dinv,
    const float* __restrict__ bb, const float* __restrict__ g,
    const float* __restrict__ be, const float* __restrict__ mm,
    const float* __restrict__ vv,
    uint4* __restrict__ H4, int n) {
  int node = (blockIdx.x * 256 + threadIdx.x) >> 6;
  if (node >= n) return;
  int lane = threadIdx.x & 63;
  int sub = lane >> 4, l16 = lane & 15;
  int beg = rowptr[node], end = rowptr[node + 1];
  float ac[8];
  #pragma unroll
  for (int j = 0; j < 8; ++j) ac[j] = 0.f;
  for (int i = beg; i < end; i += 4) {
    int idx = i + sub;
    if (idx < end) {
      int s = se[idx].x;
      uint4 p = XW4[(size_t)s * 16 + l16];
      float f[8];
      unpack8(p, f);
      #pragma unroll
      for (int j = 0; j < 8; ++j) ac[j] += f[j];
    }
  }
  // reduce across the 4 sub-groups
  #pragma unroll
  for (int j = 0; j < 8; ++j) {
    ac[j] += __shfl_xor(ac[j], 16);
    ac[j] += __shfl_xor(ac[j], 32);
  }
  // self term (identical in all lanes of same l16)
  {
    uint4 p = XW4[(size_t)node * 16 + l16];
    float f[8];
    unpack8(p, f);
    #pragma unroll
    for (int j = 0; j < 8; ++j) ac[j] += f[j];
  }
  float dn = dinv[node];
  int c = l16 * 8;
  float4 g0 = *(const float4*)&g[c],  g1 = *(const float4*)&g[c + 4];
  float4 v0 = *(const float4*)&vv[c], v1 = *(const float4*)&vv[c + 4];
  float4 b0 = *(const float4*)&bb[c], b1 = *(const float4*)&bb[c + 4];
  float4 m0 = *(const float4*)&mm[c], m1 = *(const float4*)&mm[c + 4];
  float4 e0 = *(const float4*)&be[c], e1 = *(const float4*)&be[c + 4];
  float gg[8] = {g0.x, g0.y, g0.z, g0.w, g1.x, g1.y, g1.z, g1.w};
  float vvv[8] = {v0.x, v0.y, v0.z, v0.w, v1.x, v1.y, v1.z, v1.w};
  float bbb[8] = {b0.x, b0.y, b0.z, b0.w, b1.x, b1.y, b1.z, b1.w};
  float mmm[8] = {m0.x, m0.y, m0.z, m0.w, m1.x, m1.y, m1.z, m1.w};
  float eee[8] = {e0.x, e0.y, e0.z, e0.w, e1.x, e1.y, e1.z, e1.w};
  u32 out[4];
  #pragma unroll
  for (int j2 = 0; j2 < 4; ++j2) {
    float o0 = (ac[2*j2]   * dn + bbb[2*j2]   - mmm[2*j2])   * (gg[2*j2]   * rsqrtf(vvv[2*j2]   + BN_EPS)) + eee[2*j2];
    float o1 = (ac[2*j2+1] * dn + bbb[2*j2+1] - mmm[2*j2+1]) * (gg[2*j2+1] * rsqrtf(vvv[2*j2+1] + BN_EPS)) + eee[2*j2+1];
    out[j2] = packbf2(fmaxf(o0, 0.f), fmaxf(o1, 0.f));
  }
  if (sub == 0) {
    uint4 pk = make_uint4(out[0], out[1], out[2], out[3]);
    H4[(size_t)node * 16 + l16] = pk;
  }
}

// --- edge MLP, node-major: wave per node, B[d] in regs, 4 edges/iteration ---
__global__ __launch_bounds__(256) void edge_mlp_k(const uint4* __restrict__ A4,
    const uint4* __restrict__ B4, const int* __restrict__ rowptr,
    const int2* __restrict__ se,
    const float* __restrict__ w2, const float* __restrict__ b2,
    float* __restrict__ out, int n) {
  int node = (blockIdx.x * 256 + threadIdx.x) >> 6;
  if (node >= n) return;
  int lane = threadIdx.x & 63;
  int sub = lane >> 4, l16 = lane & 15;
  int beg = rowptr[node], end = rowptr[node + 1];
  if (beg >= end) return;
  float bvals[8];
  unpack8(B4[(size_t)node * 16 + l16], bvals);
  int c = l16 * 8;
  float4 w0 = *(const float4*)&w2[c];
  float4 w1 = *(const float4*)&w2[c + 4];
  float wv[8] = {w0.x, w0.y, w0.z, w0.w, w1.x, w1.y, w1.z, w1.w};
  float bias2 = b2[0];
  for (int i = beg; i < end; i += 4) {
    int idx = i + sub;
    if (idx < end) {
      int2 pe = se[idx];
      uint4 pa = A4[(size_t)pe.x * 16 + l16];
      float f[8];
      unpack8(pa, f);
      float dot = 0.f;
      #pragma unroll
      for (int j = 0; j < 8; ++j)
        dot = fmaf(fmaxf(f[j] + bvals[j], 0.f), wv[j], dot);
      dot += __shfl_xor(dot, 1);
      dot += __shfl_xor(dot, 2);
      dot += __shfl_xor(dot, 4);
      dot += __shfl_xor(dot, 8);
      if (l16 == 0) {
        float z = dot + bias2;
        out[pe.y] = 1.f / (1.f + expf(-z));
      }
    }
  }
}

extern "C" void kernel_launch(void* const* d_in, const int* in_sizes, int n_in,
                              void* d_out, int out_size, void* d_ws, size_t ws_size,
                              hipStream_t stream) {
  const float* x    = (const float*)d_in[0];
  const int*   ei   = (const int*)d_in[1];
  const float* W1   = (const float*)d_in[2];
  const float* b1   = (const float*)d_in[3];
  const float* g1   = (const float*)d_in[4];
  const float* be1  = (const float*)d_in[5];
  const float* m1   = (const float*)d_in[6];
  const float* v1   = (const float*)d_in[7];
  const float* W2   = (const float*)d_in[8];
  const float* b2   = (const float*)d_in[9];
  const float* g2   = (const float*)d_in[10];
  const float* be2  = (const float*)d_in[11];
  const float* m2   = (const float*)d_in[12];
  const float* v2   = (const float*)d_in[13];
  const float* epW1 = (const float*)d_in[14];
  const float* epb1 = (const float*)d_in[15];
  const float* epW2 = (const float*)d_in[16];
  const float* epb2 = (const float*)d_in[17];

  int N = in_sizes[0] / 128;
  int E = in_sizes[1] / 2;
  const int* src = ei;
  const int* dst = ei + E;

  char* w = (char*)d_ws;
  size_t off = 0;
  auto carve = [&](size_t bytes) {
    void* p = w + off;
    off = (off + bytes + 255) & ~(size_t)255;
    return p;
  };
  u16* bufX  = (u16*)carve((size_t)N * 128 * 2);  // xw' -> t2' -> A
  u16* bufH  = (u16*)carve((size_t)N * 128 * 2);  // h1 -> h2
  u16* bufB  = (u16*)carve((size_t)N * 128 * 2);  // B
  int*   cnt   = (int*)carve((size_t)N * 4);
  int*   pintra= (int*)carve((size_t)E * 4);
  int*   rowptr= (int*)carve((size_t)(N + 1) * 4);
  float* dinv  = (float*)carve((size_t)N * 4);
  int2*  se    = (int2*)carve((size_t)E * 8);
  int*   bsum  = (int*)carve((size_t)1024 * 4);
  u16*   wsT   = (u16*)carve((size_t)4 * 16384 * 2);  // 4 transposed bf16 weights
  (void)ws_size; (void)n_in; (void)out_size;

  int nb = (N + 255) / 256;
  int T = (E + 3) / 4;
  int tb = (T + 255) / 256;

  hipMemsetAsync(cnt, 0, (size_t)N * 4, stream);
  wconv_k<<<256, 256, 0, stream>>>(W1, W2, epW1, wsT);
  count_pos_k<<<tb, 256, 0, stream>>>(dst, cnt, pintra, T, E);
  blocksum_k<<<nb, 256, 0, stream>>>(cnt, bsum, N);
  scan_bsum_k<<<1, 1024, 0, stream>>>(bsum, nb);
  scan_final_k<<<nb, 256, 0, stream>>>(cnt, bsum, rowptr, dinv, N);
  fill_csr_k<<<tb, 256, 0, stream>>>(src, dst, rowptr, pintra, se, T, E);

  int gb = (N + 63) / 64;
  int ab = (N + 3) / 4;   // wave-per-node kernels
  const u16* WtW1 = wsT;
  const u16* WtW2 = wsT + 16384;
  const u16* WtA  = wsT + 2 * 16384;
  const u16* WtB  = wsT + 3 * 16384;

  // layer 1: XW' = dinv * (x @ W1)
  gemm_mfma_k<false, true, false><<<gb, 256, 0, stream>>>(x, WtW1, nullptr, dinv, bufX, N);
  agg_bn_relu_k<<<ab, 256, 0, stream>>>((const uint4*)bufX, rowptr, se, dinv,
                                        b1, g1, be1, m1, v1, (uint4*)bufH, N);
  // layer 2
  gemm_mfma_k<true, true, false><<<gb, 256, 0, stream>>>(bufH, WtW2, nullptr, dinv, bufX, N);
  agg_bn_relu_k<<<ab, 256, 0, stream>>>((const uint4*)bufX, rowptr, se, dinv,
                                        b2, g2, be2, m2, v2, (uint4*)bufH, N);
  // edge predictor: A = h2 @ epW1[:128] + epb1 ; B = h2 @ epW1[128:]  (fused)
  gemm_mfma2_k<<<gb, 256, 0, stream>>>(bufH, WtA, WtB, epb1, bufX, bufB, N);
  // per-edge MLP + sigmoid, node-major (B row in regs, only A gathered)
  edge_mlp_k<<<ab, 256, 0, stream>>>((const uint4*)bufX, (const uint4*)bufB,
                                     rowptr, se, epW2, epb2, (float*)d_out, N);
}